// Round 4
// baseline (1049.278 us; speedup 1.0000x reference)
//
#include <hip/hip_runtime.h>
#include <math.h>

#define H 128
#define NHD 8
#define DH 16
#define RB 6
#define NBI 2
#define BSG 16
#define LBLK 64
#define KATOM 16
#define NBLKT 1024
#define NA 16384
#define NE 262144
#define EBE 512

__device__ __forceinline__ float atomAddF(float* p, float v) {
#if defined(__gfx90a__) || defined(__gfx940__) || defined(__gfx941__) || defined(__gfx942__) || defined(__gfx950__)
  return unsafeAtomicAdd(p, v);
#else
  return atomicAdd(p, v);
#endif
}

// ---------------- embedding ----------------
__global__ __launch_bounds__(256) void k_embed(
    const int* __restrict__ A, const int* __restrict__ apos,
    const int* __restrict__ btypes,
    const float* __restrict__ emb_atom, const float* __restrict__ emb_pos,
    const float* __restrict__ emb_block, float* __restrict__ x)
{
  int idx = blockIdx.x * 256 + threadIdx.x;   // over NA*H
  int n = idx >> 7, h = idx & 127;
  x[idx] = emb_atom[A[n] * H + h] + emb_pos[apos[n] * H + h]
         + emb_block[btypes[n >> 4] * H + h];
}

// ---------------- rbf + edge counts ----------------
__global__ __launch_bounds__(256) void k_rbf(
    const int* __restrict__ ei, const int* __restrict__ ej,
    const float* __restrict__ coords, const float* __restrict__ freq,
    float* __restrict__ rbf, float* __restrict__ cntf)
{
  int e = blockIdx.x * 256 + threadIdx.x;
  int i = ei[e], j = ej[e];
  float dx = coords[i*3+0] - coords[j*3+0];
  float dy = coords[i*3+1] - coords[j*3+1];
  float dz = coords[i*3+2] - coords[j*3+2];
  float d = sqrtf(dx*dx + dy*dy + dz*dz);
  float u = fmaxf(d * 0.125f, 1e-3f);
  float u2 = u*u, u4 = u2*u2, u5 = u4*u, u6 = u5*u, u7 = u6*u;
  float env = 1.0f/u - 28.0f*u5 + 48.0f*u6 - 21.0f*u7;
  #pragma unroll
  for (int r = 0; r < RB; ++r)
    rbf[(size_t)e*RB + r] = env * sinf(freq[r] * u);
  atomAddF(&cntf[i], 1.0f);
}

// ---------------- per-edge hidden + scatter ----------------
__global__ __launch_bounds__(256) void k_edge_pass(
    const float* __restrict__ P, const float* __restrict__ Q,
    const float* __restrict__ rbf, const float* __restrict__ W1c,
    const int* __restrict__ ei, const int* __restrict__ ej,
    float* __restrict__ Hagg)
{
  __shared__ float w[RB * H];
  for (int idx = threadIdx.x; idx < RB * H; idx += 256) w[idx] = W1c[idx];
  __syncthreads();
  int c = threadIdx.x & 127, sub = threadIdx.x >> 7;
  int e0 = blockIdx.x * 16 + sub * 8;
  for (int t = 0; t < 8; ++t) {
    int e = e0 + t;
    int i = ei[e], j = ej[e];
    float v = P[(size_t)i*H + c] + Q[(size_t)j*H + c];
    #pragma unroll
    for (int r = 0; r < RB; ++r)
      v += rbf[(size_t)e*RB + r] * w[r*H + c];
    float hv = v / (1.0f + expf(-v));   // silu
    atomAddF(&Hagg[(size_t)i*H + c], hv);
  }
}

// ---------------- generic 128-col GEMM ----------------
// C[m, ccol0+c] = act( (A1|A2)[m,:] @ W[:, wcol0+c] + bias[c]*bias_scale[m] ) + res[m,c]
__global__ __launch_bounds__(256) void gemm128(
    const float* __restrict__ A1, const float* __restrict__ A2,
    const float* __restrict__ W, int ldw, int wcol0,
    const float* __restrict__ bias, const float* __restrict__ bias_scale,
    const float* __restrict__ res,
    float* __restrict__ C, int ldc, int ccol0,
    int M, int Ktot, int act)
{
  __shared__ float As[32][256];
  __shared__ float Ws[16][128];
  int tid = threadIdx.x;
  int m0 = blockIdx.x * 32;
  for (int idx = tid; idx < 32*32; idx += 256) {
    int r = idx >> 5, k4 = idx & 31;
    float4 v = *(const float4*)&A1[(size_t)(m0 + r)*H + k4*4];
    *(float4*)&As[r][k4*4] = v;
  }
  if (A2) {
    for (int idx = tid; idx < 32*32; idx += 256) {
      int r = idx >> 5, k4 = idx & 31;
      float4 v = *(const float4*)&A2[(size_t)(m0 + r)*H + k4*4];
      *(float4*)&As[r][128 + k4*4] = v;
    }
  }
  int rr = tid >> 5;    // 0..7
  int cq = tid & 31;    // col quad
  float acc[4][4] = {};
  for (int kk0 = 0; kk0 < Ktot; kk0 += 16) {
    __syncthreads();
    for (int idx = tid; idx < 16*32; idx += 256) {
      int kr = idx >> 5, c4 = idx & 31;
      float4 v = *(const float4*)&W[(size_t)(kk0 + kr)*ldw + wcol0 + c4*4];
      *(float4*)&Ws[kr][c4*4] = v;
    }
    __syncthreads();
    #pragma unroll
    for (int kr = 0; kr < 16; ++kr) {
      float4 w = *(const float4*)&Ws[kr][cq*4];
      #pragma unroll
      for (int i = 0; i < 4; ++i) {
        float a = As[rr + 8*i][kk0 + kr];
        acc[i][0] += a * w.x; acc[i][1] += a * w.y;
        acc[i][2] += a * w.z; acc[i][3] += a * w.w;
      }
    }
  }
  #pragma unroll
  for (int i = 0; i < 4; ++i) {
    int m = m0 + rr + 8*i;
    float bs = bias_scale ? bias_scale[m] : 1.0f;
    float4 out;
    float* po = &out.x;
    #pragma unroll
    for (int j = 0; j < 4; ++j) {
      int c = cq*4 + j;
      float v = acc[i][j];
      if (bias) v += bias[c] * bs;
      if (act == 1) v = v / (1.0f + expf(-v));
      else if (act == 2) v = fmaxf(v, 0.0f);
      if (res) v += res[(size_t)m*H + c];
      po[j] = v;
    }
    *(float4*)&C[(size_t)m*ldc + ccol0 + cq*4] = out;
  }
}

// ---------------- block mean over K atoms ----------------
__global__ __launch_bounds__(256) void k_block_mean(
    const float* __restrict__ x, float* __restrict__ blocks)
{
  int idx = blockIdx.x * 256 + threadIdx.x;   // over NBLKT*H
  int nb = idx >> 7, h = idx & 127;
  float s = 0.0f;
  #pragma unroll
  for (int k = 0; k < KATOM; ++k)
    s += x[(size_t)(nb*KATOM + k)*H + h];
  blocks[idx] = s * (1.0f / KATOM);
}

// ---------------- block-edge pre-activation gather ----------------
__global__ __launch_bounds__(256) void k_gather_pre(
    const float* __restrict__ Pb, const float* __restrict__ Qb,
    const int* __restrict__ bedges, float* __restrict__ Epre)
{
  int idx = blockIdx.x * 256 + threadIdx.x;   // over BSG*EBE*H
  int row = idx >> 7, c = idx & 127;
  int g = row >> 9;
  int src = bedges[row*2], dst = bedges[row*2 + 1];
  float v = Pb[(size_t)(g*LBLK + src)*H + c] + Qb[(size_t)(g*LBLK + dst)*H + c];
  Epre[idx] = fmaxf(v, 0.0f);
}

__global__ __launch_bounds__(256) void k_cntb(
    const int* __restrict__ bedges, float* __restrict__ cntb)
{
  int idx = blockIdx.x * 256 + threadIdx.x;   // over BSG*EBE
  int g = idx >> 9;
  int src = bedges[idx*2];
  atomAddF(&cntb[g*LBLK + src], 1.0f);
}

// ---------------- MHA v3: thread-per-row, two-pass, scalar K/V streaming ----------------
// Rows grouped (b,h,s) with s fastest; S multiple of 64 -> (b,h) wave-uniform.
// K column for (b,h,j) is 16 contiguous floats in qkv -> scalar s_load broadcast.
// MODE 0: scatter-add row-output into outbuf[(b*LBLK+src)*H + h*16+d]
// MODE 1: add row-output/64 into outbuf[b*H + h*16+d]
template <int S, int MODE>
__global__ __launch_bounds__(256) void k_attn3(
    const float* __restrict__ qkv,
    const int* __restrict__ bedges,
    float* __restrict__ outbuf)
{
  int g = blockIdx.x * 256 + threadIdx.x;
  int s = g & (S - 1);
  int bh = g / S;              // wave-uniform (S % 64 == 0)
  int b = __builtin_amdgcn_readfirstlane(bh >> 3);
  int h = __builtin_amdgcn_readfirstlane(bh & 7);
  const float* base = qkv + (size_t)b * S * 384;
  const float* kbase = base + 128 + h * DH;   // K col j: kbase + j*384 (16 contig floats)
  const float* vbase = base + 256 + h * DH;
  // load q (per-lane)
  const float4* qp = (const float4*)(base + (size_t)s * 384 + h * DH);
  float4 q0 = qp[0], q1 = qp[1], q2 = qp[2], q3 = qp[3];
  float q[DH] = {q0.x,q0.y,q0.z,q0.w, q1.x,q1.y,q1.z,q1.w,
                 q2.x,q2.y,q2.z,q2.w, q3.x,q3.y,q3.z,q3.w};
  // pass 1: raw-score max
  float m = -1e30f;
  #pragma unroll 4
  for (int j = 0; j < S; ++j) {
    const float* kc = kbase + (size_t)j * 384;
    float s0 = 0.0f, s1 = 0.0f, s2 = 0.0f, s3 = 0.0f;
    #pragma unroll
    for (int d = 0; d < 4; ++d) {
      s0 += q[d]      * kc[d];
      s1 += q[4 + d]  * kc[4 + d];
      s2 += q[8 + d]  * kc[8 + d];
      s3 += q[12 + d] * kc[12 + d];
    }
    m = fmaxf(m, (s0 + s1) + (s2 + s3));
  }
  // pass 2: recompute scores, exp, accumulate PV
  float l = 0.0f;
  float o[DH] = {};
  #pragma unroll 2
  for (int j = 0; j < S; ++j) {
    const float* kc = kbase + (size_t)j * 384;
    const float* vc = vbase + (size_t)j * 384;
    float s0 = 0.0f, s1 = 0.0f, s2 = 0.0f, s3 = 0.0f;
    #pragma unroll
    for (int d = 0; d < 4; ++d) {
      s0 += q[d]      * kc[d];
      s1 += q[4 + d]  * kc[4 + d];
      s2 += q[8 + d]  * kc[8 + d];
      s3 += q[12 + d] * kc[12 + d];
    }
    float sc = (s0 + s1) + (s2 + s3);
    float p = __expf((sc - m) * 0.25f);   // 1/sqrt(16) folded into exp arg
    l += p;
    #pragma unroll
    for (int d = 0; d < DH; ++d) o[d] += p * vc[d];
  }
  float inv = 1.0f / l;
  if (MODE == 0) {
    int src = bedges[((size_t)b * S + s) * 2];
    float* dst = outbuf + (size_t)(b * LBLK + src) * H + h * DH;
    #pragma unroll
    for (int d = 0; d < DH; ++d) atomAddF(&dst[d], o[d] * inv);
  } else {
    float* dst = outbuf + (size_t)b * H + h * DH;
    #pragma unroll
    for (int d = 0; d < DH; ++d) atomAddF(&dst[d], o[d] * inv * (1.0f / 64.0f));
  }
}

__global__ __launch_bounds__(256) void k_scale_bsum(
    float* __restrict__ bsum, const float* __restrict__ cntb,
    float* __restrict__ ind)
{
  int idx = blockIdx.x * 256 + threadIdx.x;   // over NBLKT*H
  int r = idx >> 7;
  float c = cntb[r];
  bsum[idx] = (c > 0.0f) ? bsum[idx] / c : 0.0f;
  if ((idx & 127) == 0) ind[r] = (c > 0.0f) ? 1.0f : 0.0f;
}

// ---------------- final: out-proj + LN + 3-layer MLP ----------------
__device__ __forceinline__ float bsum128(float v, float* red) {
  int t = threadIdx.x;
  red[t] = v; __syncthreads();
  #pragma unroll
  for (int off = 64; off > 0; off >>= 1) {
    if (t < off) red[t] += red[t + off];
    __syncthreads();
  }
  float s = red[0];
  __syncthreads();
  return s;
}

__global__ __launch_bounds__(128) void k_final(
    const float* __restrict__ m2, const float* __restrict__ out_w,
    const float* __restrict__ out_b, const float* __restrict__ lng,
    const float* __restrict__ lnb, const float* __restrict__ w1,
    const float* __restrict__ b1, const float* __restrict__ w2,
    const float* __restrict__ b2, const float* __restrict__ w3,
    const float* __restrict__ b3, float* __restrict__ out)
{
  __shared__ float buf[128];
  __shared__ float red[128];
  int b = blockIdx.x, t = threadIdx.x;
  buf[t] = m2[b*H + t];
  __syncthreads();
  float g = out_b[t];
  for (int k = 0; k < H; ++k) g += buf[k] * out_w[k*H + t];
  float mu = bsum128(g, red) * (1.0f / H);
  float df = g - mu;
  float var = bsum128(df * df, red) * (1.0f / H);
  float gn = df / sqrtf(var + 1e-5f) * lng[t] + lnb[t];
  __syncthreads();
  buf[t] = gn; __syncthreads();
  float h1 = b1[t];
  for (int k = 0; k < H; ++k) h1 += buf[k] * w1[k*H + t];
  h1 = fmaxf(h1, 0.0f);
  __syncthreads();
  buf[t] = h1; __syncthreads();
  float h2 = b2[t];
  for (int k = 0; k < H; ++k) h2 += buf[k] * w2[k*H + t];
  h2 = fmaxf(h2, 0.0f);
  float tot = bsum128(h2 * w3[t], red);
  if (t == 0) out[b] = tot + b3[0];
}

extern "C" void kernel_launch(void* const* d_in, const int* in_sizes, int n_in,
                              void* d_out, int out_size, void* d_ws, size_t ws_size,
                              hipStream_t stream) {
  (void)in_sizes; (void)n_in; (void)out_size; (void)ws_size;
  const int*   A          = (const int*)d_in[0];
  const int*   apos       = (const int*)d_in[1];
  const int*   btypes     = (const int*)d_in[2];
  const float* coords     = (const float*)d_in[3];
  const int*   edge_index = (const int*)d_in[4];
  const int*   bedges     = (const int*)d_in[5];
  const float* emb_atom   = (const float*)d_in[6];
  const float* emb_pos    = (const float*)d_in[7];
  const float* emb_block  = (const float*)d_in[8];
  const float* rbf_freq   = (const float*)d_in[9];
  const float* inter_w1   = (const float*)d_in[10];
  const float* inter_b1   = (const float*)d_in[11];
  const float* inter_w2   = (const float*)d_in[12];
  const float* inter_b2   = (const float*)d_in[13];
  const float* upd_w1     = (const float*)d_in[14];
  const float* upd_b1     = (const float*)d_in[15];
  const float* upd_w2     = (const float*)d_in[16];
  const float* upd_b2     = (const float*)d_in[17];
  const float* edge_w1    = (const float*)d_in[18];
  const float* edge_b1    = (const float*)d_in[19];
  const float* edge_w2    = (const float*)d_in[20];
  const float* edge_b2    = (const float*)d_in[21];
  const float* attn_in_w  = (const float*)d_in[22];
  const float* attn_in_b  = (const float*)d_in[23];
  const float* attn_out_w = (const float*)d_in[24];
  const float* attn_out_b = (const float*)d_in[25];
  const float* ln_g       = (const float*)d_in[26];
  const float* ln_b       = (const float*)d_in[27];
  const float* fin_w1     = (const float*)d_in[28];
  const float* fin_b1     = (const float*)d_in[29];
  const float* fin_w2     = (const float*)d_in[30];
  const float* fin_b2     = (const float*)d_in[31];
  const float* fin_w3     = (const float*)d_in[32];
  const float* fin_b3     = (const float*)d_in[33];
  float* out = (float*)d_out;

  float* ws = (float*)d_ws;
  float* x      = ws + 0;
  float* P      = ws + 2097152;
  float* Q      = ws + 4194304;
  float* Hagg   = ws + 6291456;
  float* rbf    = ws + 8388608;    // E*6
  float* cntf   = ws + 9961472;    // NA
  float* blocks = ws + 9977856;    // NBLKT*H
  float* Pb     = ws + 10108928;
  float* Qb     = ws + 10240000;
  float* Epre   = ws + 10371072;   // BSG*EBE*H
  float* ef2    = ws + 11419648;
  float* qkv    = ws + 12468224;   // BSG*EBE*384 (reused for qkv2)
  float* bsum   = ws + 15613952;   // NBLKT*H
  float* cntb   = ws + 15745024;   // NBLKT
  float* ind    = ws + 15746048;   // NBLKT
  float* m2     = ws + 15747072;   // BSG*H

  const int* ei = edge_index;
  const int* ej = edge_index + NE;

  (void)hipMemsetAsync(cntf, 0, NA * sizeof(float), stream);
  k_embed<<<NA*H/256, 256, 0, stream>>>(A, apos, btypes, emb_atom, emb_pos, emb_block, x);
  k_rbf<<<NE/256, 256, 0, stream>>>(ei, ej, coords, rbf_freq, rbf, cntf);

  for (int b = 0; b < NBI; ++b) {
    const float* w1 = inter_w1 + (size_t)b * 262 * H;
    // P = x@W1a + b1 ; Q = x@W1b
    gemm128<<<NA/32, 256, 0, stream>>>(x, nullptr, w1, H, 0, inter_b1 + b*H,
                                       nullptr, nullptr, P, H, 0, NA, H, 0);
    gemm128<<<NA/32, 256, 0, stream>>>(x, nullptr, w1 + 128*H, H, 0, nullptr,
                                       nullptr, nullptr, Q, H, 0, NA, H, 0);
    (void)hipMemsetAsync(Hagg, 0, (size_t)NA * H * sizeof(float), stream);
    k_edge_pass<<<NE/16, 256, 0, stream>>>(P, Q, rbf, w1 + 256*H, ei, ej, Hagg);
    // agg = Hagg@W2 + cnt*b2  -> into P
    gemm128<<<NA/32, 256, 0, stream>>>(Hagg, nullptr, inter_w2 + (size_t)b*H*H, H, 0,
                                       inter_b2 + b*H, cntf, nullptr, P, H, 0, NA, H, 0);
    // U = silu([x|agg]@upd_w1 + b1) -> into Q
    gemm128<<<NA/32, 256, 0, stream>>>(x, P, upd_w1 + (size_t)b*2*H*H, H, 0,
                                       upd_b1 + b*H, nullptr, nullptr, Q, H, 0, NA, 2*H, 1);
    // x = U@upd_w2 + b2 + x
    gemm128<<<NA/32, 256, 0, stream>>>(Q, nullptr, upd_w2 + (size_t)b*H*H, H, 0,
                                       upd_b2 + b*H, nullptr, x, x, H, 0, NA, H, 0);
  }

  k_block_mean<<<NBLKT*H/256, 256, 0, stream>>>(x, blocks);
  gemm128<<<NBLKT/32, 256, 0, stream>>>(blocks, nullptr, edge_w1, H, 0, edge_b1,
                                        nullptr, nullptr, Pb, H, 0, NBLKT, H, 0);
  gemm128<<<NBLKT/32, 256, 0, stream>>>(blocks, nullptr, edge_w1 + 128*H, H, 0, nullptr,
                                        nullptr, nullptr, Qb, H, 0, NBLKT, H, 0);
  k_gather_pre<<<BSG*EBE*H/256, 256, 0, stream>>>(Pb, Qb, bedges, Epre);
  gemm128<<<BSG*EBE/32, 256, 0, stream>>>(Epre, nullptr, edge_w2, H, 0, edge_b2,
                                          nullptr, nullptr, ef2, H, 0, BSG*EBE, H, 0);
  for (int c0 = 0; c0 < 384; c0 += 128)
    gemm128<<<BSG*EBE/32, 256, 0, stream>>>(ef2, nullptr, attn_in_w, 384, c0,
                                            attn_in_b + c0, nullptr, nullptr,
                                            qkv, 384, c0, BSG*EBE, H, 0);
  (void)hipMemsetAsync(bsum, 0, (size_t)(131072 + 1024 + 1024 + 2048) * sizeof(float), stream);
  k_cntb<<<BSG*EBE/256, 256, 0, stream>>>(bedges, cntb);
  k_attn3<EBE, 0><<<BSG*NHD*EBE/256, 256, 0, stream>>>(qkv, bedges, bsum);
  k_scale_bsum<<<NBLKT*H/256, 256, 0, stream>>>(bsum, cntb, ind);
  // blocks += (bsum/cnt)@out_w + out_b*[cnt>0]
  gemm128<<<NBLKT/32, 256, 0, stream>>>(bsum, nullptr, attn_out_w, H, 0, attn_out_b,
                                        ind, blocks, blocks, H, 0, NBLKT, H, 0);
  for (int c0 = 0; c0 < 384; c0 += 128)
    gemm128<<<NBLKT/32, 256, 0, stream>>>(blocks, nullptr, attn_in_w, 384, c0,
                                          attn_in_b + c0, nullptr, nullptr,
                                          qkv, 384, c0, NBLKT, H, 0);
  k_attn3<LBLK, 1><<<BSG*NHD*LBLK/256, 256, 0, stream>>>(qkv, nullptr, m2);
  k_final<<<BSG, 128, 0, stream>>>(m2, attn_out_w, attn_out_b, ln_g, ln_b,
                                   fin_w1, fin_b1, fin_w2, fin_b2, fin_w3, fin_b3, out);
}

// Round 5
// 934.131 us; speedup vs baseline: 1.1233x; 1.1233x over previous
//
#include <hip/hip_runtime.h>
#include <math.h>

#define H 128
#define NHD 8
#define DH 16
#define RB 6
#define NBI 2
#define BSG 16
#define LBLK 64
#define KATOM 16
#define NBLKT 1024
#define NA 16384
#define NE 262144
#define EBE 512

__device__ __forceinline__ float atomAddF(float* p, float v) {
#if defined(__gfx90a__) || defined(__gfx940__) || defined(__gfx941__) || defined(__gfx942__) || defined(__gfx950__)
  return unsafeAtomicAdd(p, v);
#else
  return atomicAdd(p, v);
#endif
}

// ---------------- embedding ----------------
__global__ __launch_bounds__(256) void k_embed(
    const int* __restrict__ A, const int* __restrict__ apos,
    const int* __restrict__ btypes,
    const float* __restrict__ emb_atom, const float* __restrict__ emb_pos,
    const float* __restrict__ emb_block, float* __restrict__ x)
{
  int idx = blockIdx.x * 256 + threadIdx.x;   // over NA*H
  int n = idx >> 7, h = idx & 127;
  x[idx] = emb_atom[A[n] * H + h] + emb_pos[apos[n] * H + h]
         + emb_block[btypes[n >> 4] * H + h];
}

// ---------------- rbf + edge counts ----------------
__global__ __launch_bounds__(256) void k_rbf(
    const int* __restrict__ ei, const int* __restrict__ ej,
    const float* __restrict__ coords, const float* __restrict__ freq,
    float* __restrict__ rbf, float* __restrict__ cntf)
{
  int e = blockIdx.x * 256 + threadIdx.x;
  int i = ei[e], j = ej[e];
  float dx = coords[i*3+0] - coords[j*3+0];
  float dy = coords[i*3+1] - coords[j*3+1];
  float dz = coords[i*3+2] - coords[j*3+2];
  float d = sqrtf(dx*dx + dy*dy + dz*dz);
  float u = fmaxf(d * 0.125f, 1e-3f);
  float u2 = u*u, u4 = u2*u2, u5 = u4*u, u6 = u5*u, u7 = u6*u;
  float env = 1.0f/u - 28.0f*u5 + 48.0f*u6 - 21.0f*u7;
  #pragma unroll
  for (int r = 0; r < RB; ++r)
    rbf[(size_t)e*RB + r] = env * sinf(freq[r] * u);
  atomAddF(&cntf[i], 1.0f);
}

// ---------------- per-edge hidden + scatter ----------------
__global__ __launch_bounds__(256) void k_edge_pass(
    const float* __restrict__ P, const float* __restrict__ Q,
    const float* __restrict__ rbf, const float* __restrict__ W1c,
    const int* __restrict__ ei, const int* __restrict__ ej,
    float* __restrict__ Hagg)
{
  __shared__ float w[RB * H];
  for (int idx = threadIdx.x; idx < RB * H; idx += 256) w[idx] = W1c[idx];
  __syncthreads();
  int c = threadIdx.x & 127, sub = threadIdx.x >> 7;
  int e0 = blockIdx.x * 16 + sub * 8;
  for (int t = 0; t < 8; ++t) {
    int e = e0 + t;
    int i = ei[e], j = ej[e];
    float v = P[(size_t)i*H + c] + Q[(size_t)j*H + c];
    #pragma unroll
    for (int r = 0; r < RB; ++r)
      v += rbf[(size_t)e*RB + r] * w[r*H + c];
    float hv = v / (1.0f + expf(-v));   // silu
    atomAddF(&Hagg[(size_t)i*H + c], hv);
  }
}

// ---------------- generic 128-col GEMM ----------------
// C[m, ccol0+c] = act( (A1|A2)[m,:] @ W[:, wcol0+c] + bias[c]*bias_scale[m] ) + res[m,c]
__global__ __launch_bounds__(256) void gemm128(
    const float* __restrict__ A1, const float* __restrict__ A2,
    const float* __restrict__ W, int ldw, int wcol0,
    const float* __restrict__ bias, const float* __restrict__ bias_scale,
    const float* __restrict__ res,
    float* __restrict__ C, int ldc, int ccol0,
    int M, int Ktot, int act)
{
  __shared__ float As[32][256];
  __shared__ float Ws[16][128];
  int tid = threadIdx.x;
  int m0 = blockIdx.x * 32;
  for (int idx = tid; idx < 32*32; idx += 256) {
    int r = idx >> 5, k4 = idx & 31;
    float4 v = *(const float4*)&A1[(size_t)(m0 + r)*H + k4*4];
    *(float4*)&As[r][k4*4] = v;
  }
  if (A2) {
    for (int idx = tid; idx < 32*32; idx += 256) {
      int r = idx >> 5, k4 = idx & 31;
      float4 v = *(const float4*)&A2[(size_t)(m0 + r)*H + k4*4];
      *(float4*)&As[r][128 + k4*4] = v;
    }
  }
  int rr = tid >> 5;    // 0..7
  int cq = tid & 31;    // col quad
  float acc[4][4] = {};
  for (int kk0 = 0; kk0 < Ktot; kk0 += 16) {
    __syncthreads();
    for (int idx = tid; idx < 16*32; idx += 256) {
      int kr = idx >> 5, c4 = idx & 31;
      float4 v = *(const float4*)&W[(size_t)(kk0 + kr)*ldw + wcol0 + c4*4];
      *(float4*)&Ws[kr][c4*4] = v;
    }
    __syncthreads();
    #pragma unroll
    for (int kr = 0; kr < 16; ++kr) {
      float4 w = *(const float4*)&Ws[kr][cq*4];
      #pragma unroll
      for (int i = 0; i < 4; ++i) {
        float a = As[rr + 8*i][kk0 + kr];
        acc[i][0] += a * w.x; acc[i][1] += a * w.y;
        acc[i][2] += a * w.z; acc[i][3] += a * w.w;
      }
    }
  }
  #pragma unroll
  for (int i = 0; i < 4; ++i) {
    int m = m0 + rr + 8*i;
    float bs = bias_scale ? bias_scale[m] : 1.0f;
    float4 out;
    float* po = &out.x;
    #pragma unroll
    for (int j = 0; j < 4; ++j) {
      int c = cq*4 + j;
      float v = acc[i][j];
      if (bias) v += bias[c] * bs;
      if (act == 1) v = v / (1.0f + expf(-v));
      else if (act == 2) v = fmaxf(v, 0.0f);
      if (res) v += res[(size_t)m*H + c];
      po[j] = v;
    }
    *(float4*)&C[(size_t)m*ldc + ccol0 + cq*4] = out;
  }
}

// ---------------- block mean over K atoms ----------------
__global__ __launch_bounds__(256) void k_block_mean(
    const float* __restrict__ x, float* __restrict__ blocks)
{
  int idx = blockIdx.x * 256 + threadIdx.x;   // over NBLKT*H
  int nb = idx >> 7, h = idx & 127;
  float s = 0.0f;
  #pragma unroll
  for (int k = 0; k < KATOM; ++k)
    s += x[(size_t)(nb*KATOM + k)*H + h];
  blocks[idx] = s * (1.0f / KATOM);
}

// ---------------- block-edge pre-activation gather ----------------
__global__ __launch_bounds__(256) void k_gather_pre(
    const float* __restrict__ Pb, const float* __restrict__ Qb,
    const int* __restrict__ bedges, float* __restrict__ Epre)
{
  int idx = blockIdx.x * 256 + threadIdx.x;   // over BSG*EBE*H
  int row = idx >> 7, c = idx & 127;
  int g = row >> 9;
  int src = bedges[row*2], dst = bedges[row*2 + 1];
  float v = Pb[(size_t)(g*LBLK + src)*H + c] + Qb[(size_t)(g*LBLK + dst)*H + c];
  Epre[idx] = fmaxf(v, 0.0f);
}

__global__ __launch_bounds__(256) void k_cntb(
    const int* __restrict__ bedges, float* __restrict__ cntb)
{
  int idx = blockIdx.x * 256 + threadIdx.x;   // over BSG*EBE
  int g = idx >> 9;
  int src = bedges[idx*2];
  atomAddF(&cntb[g*LBLK + src], 1.0f);
}

// ---------------- MHA v4: thread-per-row, key-split partials, LDS K/V ----------------
// Grid: bh(128) x KS key-splits x (S/256) row chunks.
// Each thread computes partial (m, l, o[16]) for its row over KP=S/KS keys; all
// K/V reads are LDS same-address broadcasts (no conflicts, no shuffles).
template <int S, int KS>
__global__ __launch_bounds__(256) void k_attn4(
    const float* __restrict__ qkv,
    float* __restrict__ pm, float* __restrict__ pl, float* __restrict__ po)
{
  constexpr int KP = S / KS;       // keys per split
  constexpr int RCH = S / 256;     // row chunks
  __shared__ float Ks[KP][DH];
  __shared__ float Vs[KP][DH];
  int idx = blockIdx.x;
  int rc = idx % RCH;
  int ks = (idx / RCH) % KS;
  int bh = idx / (RCH * KS);
  int b = bh >> 3, h = bh & 7;
  const float* base = qkv + (size_t)b * S * 384;
  int tid = threadIdx.x;
  for (int t = tid; t < KP * 4; t += 256) {
    int j = t >> 2, d4 = t & 3;
    int jg = ks * KP + j;
    *(float4*)&Ks[j][d4*4] = *(const float4*)(base + (size_t)jg*384 + 128 + h*DH + d4*4);
    *(float4*)&Vs[j][d4*4] = *(const float4*)(base + (size_t)jg*384 + 256 + h*DH + d4*4);
  }
  __syncthreads();
  int s = rc * 256 + tid;
  const float4* qp = (const float4*)(base + (size_t)s * 384 + h * DH);
  float4 q0 = qp[0], q1 = qp[1], q2 = qp[2], q3 = qp[3];
  float q[DH] = {q0.x,q0.y,q0.z,q0.w, q1.x,q1.y,q1.z,q1.w,
                 q2.x,q2.y,q2.z,q2.w, q3.x,q3.y,q3.z,q3.w};
  float m = -1e30f;
  #pragma unroll 4
  for (int j = 0; j < KP; ++j) {
    float s0 = 0.0f, s1 = 0.0f, s2 = 0.0f, s3 = 0.0f;
    #pragma unroll
    for (int d = 0; d < 4; ++d) {
      s0 += q[d]      * Ks[j][d];
      s1 += q[4 + d]  * Ks[j][4 + d];
      s2 += q[8 + d]  * Ks[j][8 + d];
      s3 += q[12 + d] * Ks[j][12 + d];
    }
    m = fmaxf(m, (s0 + s1) + (s2 + s3));
  }
  float l = 0.0f;
  float o[DH] = {};
  #pragma unroll 2
  for (int j = 0; j < KP; ++j) {
    float s0 = 0.0f, s1 = 0.0f, s2 = 0.0f, s3 = 0.0f;
    #pragma unroll
    for (int d = 0; d < 4; ++d) {
      s0 += q[d]      * Ks[j][d];
      s1 += q[4 + d]  * Ks[j][4 + d];
      s2 += q[8 + d]  * Ks[j][8 + d];
      s3 += q[12 + d] * Ks[j][12 + d];
    }
    float sc = (s0 + s1) + (s2 + s3);
    float p = __expf((sc - m) * 0.25f);   // 1/sqrt(16) folded in
    l += p;
    #pragma unroll
    for (int d = 0; d < DH; ++d) o[d] += p * Vs[j][d];
  }
  size_t R = (size_t)bh * S + s;
  size_t pidx = R * KS + ks;
  pm[pidx] = m;
  pl[pidx] = l;
  float* op = po + pidx * DH;
  #pragma unroll
  for (int d4 = 0; d4 < 4; ++d4) {
    float4 v = {o[d4*4+0], o[d4*4+1], o[d4*4+2], o[d4*4+3]};
    *(float4*)&op[d4*4] = v;
  }
}

// combine KS partials per row, then scatter-add (same semantics as before)
template <int S, int KS>
__global__ __launch_bounds__(256) void k_attn4c(
    const float* __restrict__ pm, const float* __restrict__ pl,
    const float* __restrict__ po,
    const int* __restrict__ bedges, float* __restrict__ outbuf)
{
  int R = blockIdx.x * 256 + threadIdx.x;   // over 128*S rows
  int bh = R / S, s = R % S;
  int b = bh >> 3, h = bh & 7;
  float m = -1e30f;
  float mv[KS];
  #pragma unroll
  for (int k = 0; k < KS; ++k) { mv[k] = pm[(size_t)R*KS + k]; m = fmaxf(m, mv[k]); }
  float l = 0.0f;
  float o[DH] = {};
  #pragma unroll
  for (int k = 0; k < KS; ++k) {
    float sc = __expf((mv[k] - m) * 0.25f);
    l += pl[(size_t)R*KS + k] * sc;
    const float* op = po + ((size_t)R*KS + k) * DH;
    #pragma unroll
    for (int d = 0; d < DH; ++d) o[d] += op[d] * sc;
  }
  float inv = 1.0f / l;
  int src = bedges[((size_t)b * S + s) * 2];
  float* dst = outbuf + (size_t)(b * LBLK + src) * H + h * DH;
  #pragma unroll
  for (int d = 0; d < DH; ++d) atomAddF(&dst[d], o[d] * inv);
}

// ---------------- MHA v3 (kept for small S, mode 1) ----------------
template <int S, int MODE>
__global__ __launch_bounds__(256) void k_attn3(
    const float* __restrict__ qkv,
    const int* __restrict__ bedges,
    float* __restrict__ outbuf)
{
  int g = blockIdx.x * 256 + threadIdx.x;
  int s = g & (S - 1);
  int bh = g / S;
  int b = __builtin_amdgcn_readfirstlane(bh >> 3);
  int h = __builtin_amdgcn_readfirstlane(bh & 7);
  const float* base = qkv + (size_t)b * S * 384;
  const float* kbase = base + 128 + h * DH;
  const float* vbase = base + 256 + h * DH;
  const float4* qp = (const float4*)(base + (size_t)s * 384 + h * DH);
  float4 q0 = qp[0], q1 = qp[1], q2 = qp[2], q3 = qp[3];
  float q[DH] = {q0.x,q0.y,q0.z,q0.w, q1.x,q1.y,q1.z,q1.w,
                 q2.x,q2.y,q2.z,q2.w, q3.x,q3.y,q3.z,q3.w};
  float m = -1e30f;
  #pragma unroll 4
  for (int j = 0; j < S; ++j) {
    const float* kc = kbase + (size_t)j * 384;
    float s0 = 0.0f, s1 = 0.0f, s2 = 0.0f, s3 = 0.0f;
    #pragma unroll
    for (int d = 0; d < 4; ++d) {
      s0 += q[d]      * kc[d];
      s1 += q[4 + d]  * kc[4 + d];
      s2 += q[8 + d]  * kc[8 + d];
      s3 += q[12 + d] * kc[12 + d];
    }
    m = fmaxf(m, (s0 + s1) + (s2 + s3));
  }
  float l = 0.0f;
  float o[DH] = {};
  #pragma unroll 2
  for (int j = 0; j < S; ++j) {
    const float* kc = kbase + (size_t)j * 384;
    const float* vc = vbase + (size_t)j * 384;
    float s0 = 0.0f, s1 = 0.0f, s2 = 0.0f, s3 = 0.0f;
    #pragma unroll
    for (int d = 0; d < 4; ++d) {
      s0 += q[d]      * kc[d];
      s1 += q[4 + d]  * kc[4 + d];
      s2 += q[8 + d]  * kc[8 + d];
      s3 += q[12 + d] * kc[12 + d];
    }
    float sc = (s0 + s1) + (s2 + s3);
    float p = __expf((sc - m) * 0.25f);
    l += p;
    #pragma unroll
    for (int d = 0; d < DH; ++d) o[d] += p * vc[d];
  }
  float inv = 1.0f / l;
  if (MODE == 0) {
    int src = bedges[((size_t)b * S + s) * 2];
    float* dst = outbuf + (size_t)(b * LBLK + src) * H + h * DH;
    #pragma unroll
    for (int d = 0; d < DH; ++d) atomAddF(&dst[d], o[d] * inv);
  } else {
    float* dst = outbuf + (size_t)b * H + h * DH;
    #pragma unroll
    for (int d = 0; d < DH; ++d) atomAddF(&dst[d], o[d] * inv * (1.0f / 64.0f));
  }
}

__global__ __launch_bounds__(256) void k_scale_bsum(
    float* __restrict__ bsum, const float* __restrict__ cntb,
    float* __restrict__ ind)
{
  int idx = blockIdx.x * 256 + threadIdx.x;   // over NBLKT*H
  int r = idx >> 7;
  float c = cntb[r];
  bsum[idx] = (c > 0.0f) ? bsum[idx] / c : 0.0f;
  if ((idx & 127) == 0) ind[r] = (c > 0.0f) ? 1.0f : 0.0f;
}

// ---------------- final: out-proj + LN + 3-layer MLP ----------------
__device__ __forceinline__ float bsum128(float v, float* red) {
  int t = threadIdx.x;
  red[t] = v; __syncthreads();
  #pragma unroll
  for (int off = 64; off > 0; off >>= 1) {
    if (t < off) red[t] += red[t + off];
    __syncthreads();
  }
  float s = red[0];
  __syncthreads();
  return s;
}

__global__ __launch_bounds__(128) void k_final(
    const float* __restrict__ m2, const float* __restrict__ out_w,
    const float* __restrict__ out_b, const float* __restrict__ lng,
    const float* __restrict__ lnb, const float* __restrict__ w1,
    const float* __restrict__ b1, const float* __restrict__ w2,
    const float* __restrict__ b2, const float* __restrict__ w3,
    const float* __restrict__ b3, float* __restrict__ out)
{
  __shared__ float buf[128];
  __shared__ float red[128];
  int b = blockIdx.x, t = threadIdx.x;
  buf[t] = m2[b*H + t];
  __syncthreads();
  float g = out_b[t];
  for (int k = 0; k < H; ++k) g += buf[k] * out_w[k*H + t];
  float mu = bsum128(g, red) * (1.0f / H);
  float df = g - mu;
  float var = bsum128(df * df, red) * (1.0f / H);
  float gn = df / sqrtf(var + 1e-5f) * lng[t] + lnb[t];
  __syncthreads();
  buf[t] = gn; __syncthreads();
  float h1 = b1[t];
  for (int k = 0; k < H; ++k) h1 += buf[k] * w1[k*H + t];
  h1 = fmaxf(h1, 0.0f);
  __syncthreads();
  buf[t] = h1; __syncthreads();
  float h2 = b2[t];
  for (int k = 0; k < H; ++k) h2 += buf[k] * w2[k*H + t];
  h2 = fmaxf(h2, 0.0f);
  float tot = bsum128(h2 * w3[t], red);
  if (t == 0) out[b] = tot + b3[0];
}

extern "C" void kernel_launch(void* const* d_in, const int* in_sizes, int n_in,
                              void* d_out, int out_size, void* d_ws, size_t ws_size,
                              hipStream_t stream) {
  (void)in_sizes; (void)n_in; (void)out_size; (void)ws_size;
  const int*   A          = (const int*)d_in[0];
  const int*   apos       = (const int*)d_in[1];
  const int*   btypes     = (const int*)d_in[2];
  const float* coords     = (const float*)d_in[3];
  const int*   edge_index = (const int*)d_in[4];
  const int*   bedges     = (const int*)d_in[5];
  const float* emb_atom   = (const float*)d_in[6];
  const float* emb_pos    = (const float*)d_in[7];
  const float* emb_block  = (const float*)d_in[8];
  const float* rbf_freq   = (const float*)d_in[9];
  const float* inter_w1   = (const float*)d_in[10];
  const float* inter_b1   = (const float*)d_in[11];
  const float* inter_w2   = (const float*)d_in[12];
  const float* inter_b2   = (const float*)d_in[13];
  const float* upd_w1     = (const float*)d_in[14];
  const float* upd_b1     = (const float*)d_in[15];
  const float* upd_w2     = (const float*)d_in[16];
  const float* upd_b2     = (const float*)d_in[17];
  const float* edge_w1    = (const float*)d_in[18];
  const float* edge_b1    = (const float*)d_in[19];
  const float* edge_w2    = (const float*)d_in[20];
  const float* edge_b2    = (const float*)d_in[21];
  const float* attn_in_w  = (const float*)d_in[22];
  const float* attn_in_b  = (const float*)d_in[23];
  const float* attn_out_w = (const float*)d_in[24];
  const float* attn_out_b = (const float*)d_in[25];
  const float* ln_g       = (const float*)d_in[26];
  const float* ln_b       = (const float*)d_in[27];
  const float* fin_w1     = (const float*)d_in[28];
  const float* fin_b1     = (const float*)d_in[29];
  const float* fin_w2     = (const float*)d_in[30];
  const float* fin_b2     = (const float*)d_in[31];
  const float* fin_w3     = (const float*)d_in[32];
  const float* fin_b3     = (const float*)d_in[33];
  float* out = (float*)d_out;

  float* ws = (float*)d_ws;
  float* x      = ws + 0;
  float* P      = ws + 2097152;
  float* Q      = ws + 4194304;
  float* Hagg   = ws + 6291456;
  float* rbf    = ws + 8388608;    // E*6
  float* cntf   = ws + 9961472;    // NA
  float* blocks = ws + 9977856;    // NBLKT*H
  float* Pb     = ws + 10108928;
  float* Qb     = ws + 10240000;
  float* Epre   = ws + 10371072;   // BSG*EBE*H
  float* ef2    = ws + 11419648;
  float* qkv    = ws + 12468224;   // BSG*EBE*384 (reused for qkv2)
  float* bsum   = ws + 15613952;   // NBLKT*H
  float* cntb   = ws + 15745024;   // NBLKT
  float* ind    = ws + 15746048;   // NBLKT
  float* m2     = ws + 15747072;   // BSG*H
  // attention partials reuse dead regions (x, P, Q are dead by attention time):
  float* part_m = ws + 0;          // 128*512*4 = 262144 floats (in x region)
  float* part_l = ws + 262144;     // 262144 floats (in x region)
  float* part_o = ws + 2097152;    // 128*512*4*16 = 4194304 floats (P+Q regions)

  const int* ei = edge_index;
  const int* ej = edge_index + NE;

  (void)hipMemsetAsync(cntf, 0, NA * sizeof(float), stream);
  k_embed<<<NA*H/256, 256, 0, stream>>>(A, apos, btypes, emb_atom, emb_pos, emb_block, x);
  k_rbf<<<NE/256, 256, 0, stream>>>(ei, ej, coords, rbf_freq, rbf, cntf);

  for (int b = 0; b < NBI; ++b) {
    const float* w1 = inter_w1 + (size_t)b * 262 * H;
    // P = x@W1a + b1 ; Q = x@W1b
    gemm128<<<NA/32, 256, 0, stream>>>(x, nullptr, w1, H, 0, inter_b1 + b*H,
                                       nullptr, nullptr, P, H, 0, NA, H, 0);
    gemm128<<<NA/32, 256, 0, stream>>>(x, nullptr, w1 + 128*H, H, 0, nullptr,
                                       nullptr, nullptr, Q, H, 0, NA, H, 0);
    (void)hipMemsetAsync(Hagg, 0, (size_t)NA * H * sizeof(float), stream);
    k_edge_pass<<<NE/16, 256, 0, stream>>>(P, Q, rbf, w1 + 256*H, ei, ej, Hagg);
    // agg = Hagg@W2 + cnt*b2  -> into P
    gemm128<<<NA/32, 256, 0, stream>>>(Hagg, nullptr, inter_w2 + (size_t)b*H*H, H, 0,
                                       inter_b2 + b*H, cntf, nullptr, P, H, 0, NA, H, 0);
    // U = silu([x|agg]@upd_w1 + b1) -> into Q
    gemm128<<<NA/32, 256, 0, stream>>>(x, P, upd_w1 + (size_t)b*2*H*H, H, 0,
                                       upd_b1 + b*H, nullptr, nullptr, Q, H, 0, NA, 2*H, 1);
    // x = U@upd_w2 + b2 + x
    gemm128<<<NA/32, 256, 0, stream>>>(Q, nullptr, upd_w2 + (size_t)b*H*H, H, 0,
                                       upd_b2 + b*H, nullptr, x, x, H, 0, NA, H, 0);
  }

  k_block_mean<<<NBLKT*H/256, 256, 0, stream>>>(x, blocks);
  gemm128<<<NBLKT/32, 256, 0, stream>>>(blocks, nullptr, edge_w1, H, 0, edge_b1,
                                        nullptr, nullptr, Pb, H, 0, NBLKT, H, 0);
  gemm128<<<NBLKT/32, 256, 0, stream>>>(blocks, nullptr, edge_w1 + 128*H, H, 0, nullptr,
                                        nullptr, nullptr, Qb, H, 0, NBLKT, H, 0);
  k_gather_pre<<<BSG*EBE*H/256, 256, 0, stream>>>(Pb, Qb, bedges, Epre);
  gemm128<<<BSG*EBE/32, 256, 0, stream>>>(Epre, nullptr, edge_w2, H, 0, edge_b2,
                                          nullptr, nullptr, ef2, H, 0, BSG*EBE, H, 0);
  for (int c0 = 0; c0 < 384; c0 += 128)
    gemm128<<<BSG*EBE/32, 256, 0, stream>>>(ef2, nullptr, attn_in_w, 384, c0,
                                            attn_in_b + c0, nullptr, nullptr,
                                            qkv, 384, c0, BSG*EBE, H, 0);
  (void)hipMemsetAsync(bsum, 0, (size_t)(131072 + 1024 + 1024 + 2048) * sizeof(float), stream);
  k_cntb<<<BSG*EBE/256, 256, 0, stream>>>(bedges, cntb);
  k_attn4<EBE, 4><<<BSG*NHD*4*(EBE/256), 256, 0, stream>>>(qkv, part_m, part_l, part_o);
  k_attn4c<EBE, 4><<<BSG*NHD*EBE/256, 256, 0, stream>>>(part_m, part_l, part_o, bedges, bsum);
  k_scale_bsum<<<NBLKT*H/256, 256, 0, stream>>>(bsum, cntb, ind);
  // blocks += (bsum/cnt)@out_w + out_b*[cnt>0]
  gemm128<<<NBLKT/32, 256, 0, stream>>>(bsum, nullptr, attn_out_w, H, 0, attn_out_b,
                                        ind, blocks, blocks, H, 0, NBLKT, H, 0);
  for (int c0 = 0; c0 < 384; c0 += 128)
    gemm128<<<NBLKT/32, 256, 0, stream>>>(blocks, nullptr, attn_in_w, 384, c0,
                                          attn_in_b + c0, nullptr, nullptr,
                                          qkv, 384, c0, NBLKT, H, 0);
  k_attn3<LBLK, 1><<<BSG*NHD*LBLK/256, 256, 0, stream>>>(qkv, nullptr, m2);
  k_final<<<BSG, 128, 0, stream>>>(m2, attn_out_w, attn_out_b, ln_g, ln_b,
                                   fin_w1, fin_b1, fin_w2, fin_b2, fin_w3, fin_b3, out);
}

// Round 6
// 848.432 us; speedup vs baseline: 1.2367x; 1.1010x over previous
//
#include <hip/hip_runtime.h>
#include <math.h>

#define H 128
#define NHD 8
#define DH 16
#define RB 6
#define NBI 2
#define BSG 16
#define LBLK 64
#define KATOM 16
#define NBLKT 1024
#define NA 16384
#define NE 262144
#define EBE 512

__device__ __forceinline__ float atomAddF(float* p, float v) {
#if defined(__gfx90a__) || defined(__gfx940__) || defined(__gfx941__) || defined(__gfx942__) || defined(__gfx950__)
  return unsafeAtomicAdd(p, v);
#else
  return atomicAdd(p, v);
#endif
}

// ---------------- embedding ----------------
__global__ __launch_bounds__(256) void k_embed(
    const int* __restrict__ A, const int* __restrict__ apos,
    const int* __restrict__ btypes,
    const float* __restrict__ emb_atom, const float* __restrict__ emb_pos,
    const float* __restrict__ emb_block, float* __restrict__ x)
{
  int idx = blockIdx.x * 256 + threadIdx.x;   // over NA*H
  int n = idx >> 7, h = idx & 127;
  x[idx] = emb_atom[A[n] * H + h] + emb_pos[apos[n] * H + h]
         + emb_block[btypes[n >> 4] * H + h];
}

// ---------------- edge sort: histogram ----------------
__global__ __launch_bounds__(256) void k_hist(
    const int* __restrict__ ei, int* __restrict__ cnt)
{
  int e = blockIdx.x * 256 + threadIdx.x;
  atomicAdd(&cnt[ei[e]], 1);
}

// ---------------- edge sort: scan (single block, 1024 thr, 16 bins each) ----
__global__ __launch_bounds__(1024) void k_scan(
    const int* __restrict__ cnt, int* __restrict__ off,
    int* __restrict__ cur, float* __restrict__ cntf)
{
  __shared__ int ps[1024];
  int t = threadIdx.x;
  int base = t * 16;
  int local[16];
  int s = 0;
  #pragma unroll
  for (int k = 0; k < 16; ++k) { local[k] = s; s += cnt[base + k]; }
  ps[t] = s;
  __syncthreads();
  for (int d = 1; d < 1024; d <<= 1) {
    int v = (t >= d) ? ps[t - d] : 0;
    __syncthreads();
    ps[t] += v;
    __syncthreads();
  }
  int offset = (t == 0) ? 0 : ps[t - 1];
  #pragma unroll
  for (int k = 0; k < 16; ++k) {
    int o = offset + local[k];
    off[base + k] = o;
    cur[base + k] = o;
    cntf[base + k] = (float)cnt[base + k];
  }
  if (t == 1023) off[NA] = offset + s;
}

// ---------------- edge sort: scatter + fused RBF ----------------
__global__ __launch_bounds__(256) void k_scatter(
    const int* __restrict__ ei, const int* __restrict__ ej,
    const float* __restrict__ coords, const float* __restrict__ freq,
    int* __restrict__ cur, int* __restrict__ ej_s, float* __restrict__ rbf_s)
{
  int e = blockIdx.x * 256 + threadIdx.x;
  int i = ei[e], j = ej[e];
  int pos = atomicAdd(&cur[i], 1);
  ej_s[pos] = j;
  float dx = coords[i*3+0] - coords[j*3+0];
  float dy = coords[i*3+1] - coords[j*3+1];
  float dz = coords[i*3+2] - coords[j*3+2];
  float d = sqrtf(dx*dx + dy*dy + dz*dz);
  float u = fmaxf(d * 0.125f, 1e-3f);
  float u2 = u*u, u4 = u2*u2, u5 = u4*u, u6 = u5*u, u7 = u6*u;
  float env = 1.0f/u - 28.0f*u5 + 48.0f*u6 - 21.0f*u7;
  #pragma unroll
  for (int r = 0; r < RB; ++r)
    rbf_s[(size_t)pos*RB + r] = env * sinf(freq[r] * u);
}

// ---------------- per-atom CSR edge pass (no atomics) ----------------
__global__ __launch_bounds__(256) void k_edge_csr(
    const float* __restrict__ P, const float* __restrict__ Q,
    const float* __restrict__ rbf_s, const float* __restrict__ W1c,
    const int* __restrict__ ej_s, const int* __restrict__ off,
    float* __restrict__ Hagg)
{
  __shared__ float w[RB * H];
  for (int idx = threadIdx.x; idx < RB * H; idx += 256) w[idx] = W1c[idx];
  __syncthreads();
  int c = threadIdx.x & 127, half = threadIdx.x >> 7;
  int i = blockIdx.x * 2 + half;
  int e0 = off[i], e1 = off[i + 1];
  float pv = P[(size_t)i * H + c];
  float w0 = w[0*H+c], w1 = w[1*H+c], w2 = w[2*H+c];
  float w3 = w[3*H+c], w4 = w[4*H+c], w5 = w[5*H+c];
  float acc = 0.0f;
  for (int e = e0; e < e1; ++e) {
    int j = ej_s[e];
    float v = pv + Q[(size_t)j * H + c];
    const float* rb = &rbf_s[(size_t)e * RB];
    v += rb[0]*w0 + rb[1]*w1 + rb[2]*w2 + rb[3]*w3 + rb[4]*w4 + rb[5]*w5;
    acc += v / (1.0f + expf(-v));   // silu
  }
  Hagg[(size_t)i * H + c] = acc;
}

// ---------------- generic 128-col GEMM ----------------
// C[m, ccol0+c] = act( (A1|A2)[m,:] @ W[:, wcol0+c] + bias[c]*bias_scale[m] ) + res[m,c]
__global__ __launch_bounds__(256) void gemm128(
    const float* __restrict__ A1, const float* __restrict__ A2,
    const float* __restrict__ W, int ldw, int wcol0,
    const float* __restrict__ bias, const float* __restrict__ bias_scale,
    const float* __restrict__ res,
    float* __restrict__ C, int ldc, int ccol0,
    int M, int Ktot, int act)
{
  __shared__ float As[32][256];
  __shared__ float Ws[16][128];
  int tid = threadIdx.x;
  int m0 = blockIdx.x * 32;
  for (int idx = tid; idx < 32*32; idx += 256) {
    int r = idx >> 5, k4 = idx & 31;
    float4 v = *(const float4*)&A1[(size_t)(m0 + r)*H + k4*4];
    *(float4*)&As[r][k4*4] = v;
  }
  if (A2) {
    for (int idx = tid; idx < 32*32; idx += 256) {
      int r = idx >> 5, k4 = idx & 31;
      float4 v = *(const float4*)&A2[(size_t)(m0 + r)*H + k4*4];
      *(float4*)&As[r][128 + k4*4] = v;
    }
  }
  int rr = tid >> 5;    // 0..7
  int cq = tid & 31;    // col quad
  float acc[4][4] = {};
  for (int kk0 = 0; kk0 < Ktot; kk0 += 16) {
    __syncthreads();
    for (int idx = tid; idx < 16*32; idx += 256) {
      int kr = idx >> 5, c4 = idx & 31;
      float4 v = *(const float4*)&W[(size_t)(kk0 + kr)*ldw + wcol0 + c4*4];
      *(float4*)&Ws[kr][c4*4] = v;
    }
    __syncthreads();
    #pragma unroll
    for (int kr = 0; kr < 16; ++kr) {
      float4 w = *(const float4*)&Ws[kr][cq*4];
      #pragma unroll
      for (int i = 0; i < 4; ++i) {
        float a = As[rr + 8*i][kk0 + kr];
        acc[i][0] += a * w.x; acc[i][1] += a * w.y;
        acc[i][2] += a * w.z; acc[i][3] += a * w.w;
      }
    }
  }
  #pragma unroll
  for (int i = 0; i < 4; ++i) {
    int m = m0 + rr + 8*i;
    float bs = bias_scale ? bias_scale[m] : 1.0f;
    float4 out;
    float* po = &out.x;
    #pragma unroll
    for (int j = 0; j < 4; ++j) {
      int c = cq*4 + j;
      float v = acc[i][j];
      if (bias) v += bias[c] * bs;
      if (act == 1) v = v / (1.0f + expf(-v));
      else if (act == 2) v = fmaxf(v, 0.0f);
      if (res) v += res[(size_t)m*H + c];
      po[j] = v;
    }
    *(float4*)&C[(size_t)m*ldc + ccol0 + cq*4] = out;
  }
}

// ---------------- block mean over K atoms ----------------
__global__ __launch_bounds__(256) void k_block_mean(
    const float* __restrict__ x, float* __restrict__ blocks)
{
  int idx = blockIdx.x * 256 + threadIdx.x;   // over NBLKT*H
  int nb = idx >> 7, h = idx & 127;
  float s = 0.0f;
  #pragma unroll
  for (int k = 0; k < KATOM; ++k)
    s += x[(size_t)(nb*KATOM + k)*H + h];
  blocks[idx] = s * (1.0f / KATOM);
}

// ---------------- block-edge pre-activation gather ----------------
__global__ __launch_bounds__(256) void k_gather_pre(
    const float* __restrict__ Pb, const float* __restrict__ Qb,
    const int* __restrict__ bedges, float* __restrict__ Epre)
{
  int idx = blockIdx.x * 256 + threadIdx.x;   // over BSG*EBE*H
  int row = idx >> 7, c = idx & 127;
  int g = row >> 9;
  int src = bedges[row*2], dst = bedges[row*2 + 1];
  float v = Pb[(size_t)(g*LBLK + src)*H + c] + Qb[(size_t)(g*LBLK + dst)*H + c];
  Epre[idx] = fmaxf(v, 0.0f);
}

__global__ __launch_bounds__(256) void k_cntb(
    const int* __restrict__ bedges, float* __restrict__ cntb)
{
  int idx = blockIdx.x * 256 + threadIdx.x;   // over BSG*EBE
  int g = idx >> 9;
  int src = bedges[idx*2];
  atomAddF(&cntb[g*LBLK + src], 1.0f);
}

// ---------------- MHA v4: thread-per-row, key-split partials, LDS K/V ----------------
template <int S, int KS>
__global__ __launch_bounds__(256) void k_attn4(
    const float* __restrict__ qkv,
    float* __restrict__ pm, float* __restrict__ pl, float* __restrict__ po)
{
  constexpr int KP = S / KS;       // keys per split
  constexpr int RCH = S / 256;     // row chunks
  __shared__ float Ks[KP][DH];
  __shared__ float Vs[KP][DH];
  int idx = blockIdx.x;
  int rc = idx % RCH;
  int ks = (idx / RCH) % KS;
  int bh = idx / (RCH * KS);
  int b = bh >> 3, h = bh & 7;
  const float* base = qkv + (size_t)b * S * 384;
  int tid = threadIdx.x;
  for (int t = tid; t < KP * 4; t += 256) {
    int j = t >> 2, d4 = t & 3;
    int jg = ks * KP + j;
    *(float4*)&Ks[j][d4*4] = *(const float4*)(base + (size_t)jg*384 + 128 + h*DH + d4*4);
    *(float4*)&Vs[j][d4*4] = *(const float4*)(base + (size_t)jg*384 + 256 + h*DH + d4*4);
  }
  __syncthreads();
  int s = rc * 256 + tid;
  const float4* qp = (const float4*)(base + (size_t)s * 384 + h * DH);
  float4 q0 = qp[0], q1 = qp[1], q2 = qp[2], q3 = qp[3];
  float q[DH] = {q0.x,q0.y,q0.z,q0.w, q1.x,q1.y,q1.z,q1.w,
                 q2.x,q2.y,q2.z,q2.w, q3.x,q3.y,q3.z,q3.w};
  float m = -1e30f;
  #pragma unroll 4
  for (int j = 0; j < KP; ++j) {
    float s0 = 0.0f, s1 = 0.0f, s2 = 0.0f, s3 = 0.0f;
    #pragma unroll
    for (int d = 0; d < 4; ++d) {
      s0 += q[d]      * Ks[j][d];
      s1 += q[4 + d]  * Ks[j][4 + d];
      s2 += q[8 + d]  * Ks[j][8 + d];
      s3 += q[12 + d] * Ks[j][12 + d];
    }
    m = fmaxf(m, (s0 + s1) + (s2 + s3));
  }
  float l = 0.0f;
  float o[DH] = {};
  #pragma unroll 2
  for (int j = 0; j < KP; ++j) {
    float s0 = 0.0f, s1 = 0.0f, s2 = 0.0f, s3 = 0.0f;
    #pragma unroll
    for (int d = 0; d < 4; ++d) {
      s0 += q[d]      * Ks[j][d];
      s1 += q[4 + d]  * Ks[j][4 + d];
      s2 += q[8 + d]  * Ks[j][8 + d];
      s3 += q[12 + d] * Ks[j][12 + d];
    }
    float sc = (s0 + s1) + (s2 + s3);
    float p = __expf((sc - m) * 0.25f);   // 1/sqrt(16) folded in
    l += p;
    #pragma unroll
    for (int d = 0; d < DH; ++d) o[d] += p * Vs[j][d];
  }
  size_t R = (size_t)bh * S + s;
  size_t pidx = R * KS + ks;
  pm[pidx] = m;
  pl[pidx] = l;
  float* op = po + pidx * DH;
  #pragma unroll
  for (int d4 = 0; d4 < 4; ++d4) {
    float4 v = {o[d4*4+0], o[d4*4+1], o[d4*4+2], o[d4*4+3]};
    *(float4*)&op[d4*4] = v;
  }
}

// combine KS partials per row, then scatter-add
template <int S, int KS>
__global__ __launch_bounds__(256) void k_attn4c(
    const float* __restrict__ pm, const float* __restrict__ pl,
    const float* __restrict__ po,
    const int* __restrict__ bedges, float* __restrict__ outbuf)
{
  int R = blockIdx.x * 256 + threadIdx.x;   // over 128*S rows
  int bh = R / S, s = R % S;
  int b = bh >> 3, h = bh & 7;
  float m = -1e30f;
  float mv[KS];
  #pragma unroll
  for (int k = 0; k < KS; ++k) { mv[k] = pm[(size_t)R*KS + k]; m = fmaxf(m, mv[k]); }
  float l = 0.0f;
  float o[DH] = {};
  #pragma unroll
  for (int k = 0; k < KS; ++k) {
    float sc = __expf((mv[k] - m) * 0.25f);
    l += pl[(size_t)R*KS + k] * sc;
    const float* op = po + ((size_t)R*KS + k) * DH;
    #pragma unroll
    for (int d = 0; d < DH; ++d) o[d] += op[d] * sc;
  }
  float inv = 1.0f / l;
  int src = bedges[((size_t)b * S + s) * 2];
  float* dst = outbuf + (size_t)(b * LBLK + src) * H + h * DH;
  #pragma unroll
  for (int d = 0; d < DH; ++d) atomAddF(&dst[d], o[d] * inv);
}

// ---------------- MHA v3 (small S, mode 1) ----------------
template <int S, int MODE>
__global__ __launch_bounds__(256) void k_attn3(
    const float* __restrict__ qkv,
    const int* __restrict__ bedges,
    float* __restrict__ outbuf)
{
  int g = blockIdx.x * 256 + threadIdx.x;
  int s = g & (S - 1);
  int bh = g / S;
  int b = __builtin_amdgcn_readfirstlane(bh >> 3);
  int h = __builtin_amdgcn_readfirstlane(bh & 7);
  const float* base = qkv + (size_t)b * S * 384;
  const float* kbase = base + 128 + h * DH;
  const float* vbase = base + 256 + h * DH;
  const float4* qp = (const float4*)(base + (size_t)s * 384 + h * DH);
  float4 q0 = qp[0], q1 = qp[1], q2 = qp[2], q3 = qp[3];
  float q[DH] = {q0.x,q0.y,q0.z,q0.w, q1.x,q1.y,q1.z,q1.w,
                 q2.x,q2.y,q2.z,q2.w, q3.x,q3.y,q3.z,q3.w};
  float m = -1e30f;
  #pragma unroll 4
  for (int j = 0; j < S; ++j) {
    const float* kc = kbase + (size_t)j * 384;
    float s0 = 0.0f, s1 = 0.0f, s2 = 0.0f, s3 = 0.0f;
    #pragma unroll
    for (int d = 0; d < 4; ++d) {
      s0 += q[d]      * kc[d];
      s1 += q[4 + d]  * kc[4 + d];
      s2 += q[8 + d]  * kc[8 + d];
      s3 += q[12 + d] * kc[12 + d];
    }
    m = fmaxf(m, (s0 + s1) + (s2 + s3));
  }
  float l = 0.0f;
  float o[DH] = {};
  #pragma unroll 2
  for (int j = 0; j < S; ++j) {
    const float* kc = kbase + (size_t)j * 384;
    const float* vc = vbase + (size_t)j * 384;
    float s0 = 0.0f, s1 = 0.0f, s2 = 0.0f, s3 = 0.0f;
    #pragma unroll
    for (int d = 0; d < 4; ++d) {
      s0 += q[d]      * kc[d];
      s1 += q[4 + d]  * kc[4 + d];
      s2 += q[8 + d]  * kc[8 + d];
      s3 += q[12 + d] * kc[12 + d];
    }
    float sc = (s0 + s1) + (s2 + s3);
    float p = __expf((sc - m) * 0.25f);
    l += p;
    #pragma unroll
    for (int d = 0; d < DH; ++d) o[d] += p * vc[d];
  }
  float inv = 1.0f / l;
  if (MODE == 0) {
    int src = bedges[((size_t)b * S + s) * 2];
    float* dst = outbuf + (size_t)(b * LBLK + src) * H + h * DH;
    #pragma unroll
    for (int d = 0; d < DH; ++d) atomAddF(&dst[d], o[d] * inv);
  } else {
    float* dst = outbuf + (size_t)b * H + h * DH;
    #pragma unroll
    for (int d = 0; d < DH; ++d) atomAddF(&dst[d], o[d] * inv * (1.0f / 64.0f));
  }
}

__global__ __launch_bounds__(256) void k_scale_bsum(
    float* __restrict__ bsum, const float* __restrict__ cntb,
    float* __restrict__ ind)
{
  int idx = blockIdx.x * 256 + threadIdx.x;   // over NBLKT*H
  int r = idx >> 7;
  float c = cntb[r];
  bsum[idx] = (c > 0.0f) ? bsum[idx] / c : 0.0f;
  if ((idx & 127) == 0) ind[r] = (c > 0.0f) ? 1.0f : 0.0f;
}

// ---------------- final: out-proj + LN + 3-layer MLP ----------------
__device__ __forceinline__ float bsum128(float v, float* red) {
  int t = threadIdx.x;
  red[t] = v; __syncthreads();
  #pragma unroll
  for (int off = 64; off > 0; off >>= 1) {
    if (t < off) red[t] += red[t + off];
    __syncthreads();
  }
  float s = red[0];
  __syncthreads();
  return s;
}

__global__ __launch_bounds__(128) void k_final(
    const float* __restrict__ m2, const float* __restrict__ out_w,
    const float* __restrict__ out_b, const float* __restrict__ lng,
    const float* __restrict__ lnb, const float* __restrict__ w1,
    const float* __restrict__ b1, const float* __restrict__ w2,
    const float* __restrict__ b2, const float* __restrict__ w3,
    const float* __restrict__ b3, float* __restrict__ out)
{
  __shared__ float buf[128];
  __shared__ float red[128];
  int b = blockIdx.x, t = threadIdx.x;
  buf[t] = m2[b*H + t];
  __syncthreads();
  float g = out_b[t];
  for (int k = 0; k < H; ++k) g += buf[k] * out_w[k*H + t];
  float mu = bsum128(g, red) * (1.0f / H);
  float df = g - mu;
  float var = bsum128(df * df, red) * (1.0f / H);
  float gn = df / sqrtf(var + 1e-5f) * lng[t] + lnb[t];
  __syncthreads();
  buf[t] = gn; __syncthreads();
  float h1 = b1[t];
  for (int k = 0; k < H; ++k) h1 += buf[k] * w1[k*H + t];
  h1 = fmaxf(h1, 0.0f);
  __syncthreads();
  buf[t] = h1; __syncthreads();
  float h2 = b2[t];
  for (int k = 0; k < H; ++k) h2 += buf[k] * w2[k*H + t];
  h2 = fmaxf(h2, 0.0f);
  float tot = bsum128(h2 * w3[t], red);
  if (t == 0) out[b] = tot + b3[0];
}

extern "C" void kernel_launch(void* const* d_in, const int* in_sizes, int n_in,
                              void* d_out, int out_size, void* d_ws, size_t ws_size,
                              hipStream_t stream) {
  (void)in_sizes; (void)n_in; (void)out_size; (void)ws_size;
  const int*   A          = (const int*)d_in[0];
  const int*   apos       = (const int*)d_in[1];
  const int*   btypes     = (const int*)d_in[2];
  const float* coords     = (const float*)d_in[3];
  const int*   edge_index = (const int*)d_in[4];
  const int*   bedges     = (const int*)d_in[5];
  const float* emb_atom   = (const float*)d_in[6];
  const float* emb_pos    = (const float*)d_in[7];
  const float* emb_block  = (const float*)d_in[8];
  const float* rbf_freq   = (const float*)d_in[9];
  const float* inter_w1   = (const float*)d_in[10];
  const float* inter_b1   = (const float*)d_in[11];
  const float* inter_w2   = (const float*)d_in[12];
  const float* inter_b2   = (const float*)d_in[13];
  const float* upd_w1     = (const float*)d_in[14];
  const float* upd_b1     = (const float*)d_in[15];
  const float* upd_w2     = (const float*)d_in[16];
  const float* upd_b2     = (const float*)d_in[17];
  const float* edge_w1    = (const float*)d_in[18];
  const float* edge_b1    = (const float*)d_in[19];
  const float* edge_w2    = (const float*)d_in[20];
  const float* edge_b2    = (const float*)d_in[21];
  const float* attn_in_w  = (const float*)d_in[22];
  const float* attn_in_b  = (const float*)d_in[23];
  const float* attn_out_w = (const float*)d_in[24];
  const float* attn_out_b = (const float*)d_in[25];
  const float* ln_g       = (const float*)d_in[26];
  const float* ln_b       = (const float*)d_in[27];
  const float* fin_w1     = (const float*)d_in[28];
  const float* fin_b1     = (const float*)d_in[29];
  const float* fin_w2     = (const float*)d_in[30];
  const float* fin_b2     = (const float*)d_in[31];
  const float* fin_w3     = (const float*)d_in[32];
  const float* fin_b3     = (const float*)d_in[33];
  float* out = (float*)d_out;

  float* ws = (float*)d_ws;
  float* x      = ws + 0;
  float* P      = ws + 2097152;
  float* Q      = ws + 4194304;
  float* Hagg   = ws + 6291456;
  float* rbf_s  = ws + 8388608;    // E*6 (sorted RBF)
  float* cntf   = ws + 9961472;    // NA
  float* blocks = ws + 9977856;    // NBLKT*H
  float* Pb     = ws + 10108928;
  float* Qb     = ws + 10240000;
  float* Epre   = ws + 10371072;   // BSG*EBE*H (also hosts sort scratch early)
  float* ef2    = ws + 11419648;
  float* qkv    = ws + 12468224;   // BSG*EBE*384
  float* bsum   = ws + 15613952;   // NBLKT*H
  float* cntb   = ws + 15745024;   // NBLKT
  float* ind    = ws + 15746048;   // NBLKT
  float* m2     = ws + 15747072;   // BSG*H
  // sort scratch lives in Epre region (dead until block-attention phase):
  int* ej_s = (int*)(ws + 10371072);          // NE ints
  int* off  = (int*)(ws + 10371072 + 262144); // NA+1 ints
  int* cur  = (int*)(ws + 10371072 + 278784); // NA ints (262144+16640 aligned)
  int* cnt  = (int*)(ws + 10371072 + 295168); // NA ints
  // attention partials reuse dead regions (x, P, Q dead by attention time):
  float* part_m = ws + 0;
  float* part_l = ws + 262144;
  float* part_o = ws + 2097152;

  const int* ei = edge_index;
  const int* ej = edge_index + NE;

  // ---- edge sort (once; reused by both interaction blocks) ----
  (void)hipMemsetAsync(cnt, 0, NA * sizeof(int), stream);
  k_hist<<<NE/256, 256, 0, stream>>>(ei, cnt);
  k_scan<<<1, 1024, 0, stream>>>(cnt, off, cur, cntf);
  k_scatter<<<NE/256, 256, 0, stream>>>(ei, ej, coords, rbf_freq, cur, ej_s, rbf_s);

  k_embed<<<NA*H/256, 256, 0, stream>>>(A, apos, btypes, emb_atom, emb_pos, emb_block, x);

  for (int b = 0; b < NBI; ++b) {
    const float* w1 = inter_w1 + (size_t)b * 262 * H;
    // P = x@W1a + b1 ; Q = x@W1b
    gemm128<<<NA/32, 256, 0, stream>>>(x, nullptr, w1, H, 0, inter_b1 + b*H,
                                       nullptr, nullptr, P, H, 0, NA, H, 0);
    gemm128<<<NA/32, 256, 0, stream>>>(x, nullptr, w1 + 128*H, H, 0, nullptr,
                                       nullptr, nullptr, Q, H, 0, NA, H, 0);
    k_edge_csr<<<NA/2, 256, 0, stream>>>(P, Q, rbf_s, w1 + 256*H, ej_s, off, Hagg);
    // agg = Hagg@W2 + cnt*b2  -> into P
    gemm128<<<NA/32, 256, 0, stream>>>(Hagg, nullptr, inter_w2 + (size_t)b*H*H, H, 0,
                                       inter_b2 + b*H, cntf, nullptr, P, H, 0, NA, H, 0);
    // U = silu([x|agg]@upd_w1 + b1) -> into Q
    gemm128<<<NA/32, 256, 0, stream>>>(x, P, upd_w1 + (size_t)b*2*H*H, H, 0,
                                       upd_b1 + b*H, nullptr, nullptr, Q, H, 0, NA, 2*H, 1);
    // x = U@upd_w2 + b2 + x
    gemm128<<<NA/32, 256, 0, stream>>>(Q, nullptr, upd_w2 + (size_t)b*H*H, H, 0,
                                       upd_b2 + b*H, nullptr, x, x, H, 0, NA, H, 0);
  }

  k_block_mean<<<NBLKT*H/256, 256, 0, stream>>>(x, blocks);
  gemm128<<<NBLKT/32, 256, 0, stream>>>(blocks, nullptr, edge_w1, H, 0, edge_b1,
                                        nullptr, nullptr, Pb, H, 0, NBLKT, H, 0);
  gemm128<<<NBLKT/32, 256, 0, stream>>>(blocks, nullptr, edge_w1 + 128*H, H, 0, nullptr,
                                        nullptr, nullptr, Qb, H, 0, NBLKT, H, 0);
  k_gather_pre<<<BSG*EBE*H/256, 256, 0, stream>>>(Pb, Qb, bedges, Epre);
  gemm128<<<BSG*EBE/32, 256, 0, stream>>>(Epre, nullptr, edge_w2, H, 0, edge_b2,
                                          nullptr, nullptr, ef2, H, 0, BSG*EBE, H, 0);
  for (int c0 = 0; c0 < 384; c0 += 128)
    gemm128<<<BSG*EBE/32, 256, 0, stream>>>(ef2, nullptr, attn_in_w, 384, c0,
                                            attn_in_b + c0, nullptr, nullptr,
                                            qkv, 384, c0, BSG*EBE, H, 0);
  (void)hipMemsetAsync(bsum, 0, (size_t)(131072 + 1024 + 1024 + 2048) * sizeof(float), stream);
  k_cntb<<<BSG*EBE/256, 256, 0, stream>>>(bedges, cntb);
  k_attn4<EBE, 4><<<BSG*NHD*4*(EBE/256), 256, 0, stream>>>(qkv, part_m, part_l, part_o);
  k_attn4c<EBE, 4><<<BSG*NHD*EBE/256, 256, 0, stream>>>(part_m, part_l, part_o, bedges, bsum);
  k_scale_bsum<<<NBLKT*H/256, 256, 0, stream>>>(bsum, cntb, ind);
  // blocks += (bsum/cnt)@out_w + out_b*[cnt>0]
  gemm128<<<NBLKT/32, 256, 0, stream>>>(bsum, nullptr, attn_out_w, H, 0, attn_out_b,
                                        ind, blocks, blocks, H, 0, NBLKT, H, 0);
  for (int c0 = 0; c0 < 384; c0 += 128)
    gemm128<<<NBLKT/32, 256, 0, stream>>>(blocks, nullptr, attn_in_w, 384, c0,
                                          attn_in_b + c0, nullptr, nullptr,
                                          qkv, 384, c0, NBLKT, H, 0);
  k_attn3<LBLK, 1><<<BSG*NHD*LBLK/256, 256, 0, stream>>>(qkv, nullptr, m2);
  k_final<<<BSG, 128, 0, stream>>>(m2, attn_out_w, attn_out_b, ln_g, ln_b,
                                   fin_w1, fin_b1, fin_w2, fin_b2, fin_w3, fin_b3, out);
}

// Round 7
// 809.936 us; speedup vs baseline: 1.2955x; 1.0475x over previous
//
#include <hip/hip_runtime.h>
#include <math.h>

#define H 128
#define NHD 8
#define DH 16
#define RB 6
#define NBI 2
#define BSG 16
#define LBLK 64
#define KATOM 16
#define NBLKT 1024
#define NA 16384
#define NE 262144
#define EBE 512

__device__ __forceinline__ float atomAddF(float* p, float v) {
#if defined(__gfx90a__) || defined(__gfx940__) || defined(__gfx941__) || defined(__gfx942__) || defined(__gfx950__)
  return unsafeAtomicAdd(p, v);
#else
  return atomicAdd(p, v);
#endif
}

// ---------------- embedding ----------------
__global__ __launch_bounds__(256) void k_embed(
    const int* __restrict__ A, const int* __restrict__ apos,
    const int* __restrict__ btypes,
    const float* __restrict__ emb_atom, const float* __restrict__ emb_pos,
    const float* __restrict__ emb_block, float* __restrict__ x)
{
  int idx = blockIdx.x * 256 + threadIdx.x;   // over NA*H
  int n = idx >> 7, h = idx & 127;
  x[idx] = emb_atom[A[n] * H + h] + emb_pos[apos[n] * H + h]
         + emb_block[btypes[n >> 4] * H + h];
}

// ---------------- edge sort: histogram ----------------
__global__ __launch_bounds__(256) void k_hist(
    const int* __restrict__ ei, int* __restrict__ cnt)
{
  int e = blockIdx.x * 256 + threadIdx.x;
  atomicAdd(&cnt[ei[e]], 1);
}

// ---------------- edge sort: scan (single block, 1024 thr, 16 bins each) ----
__global__ __launch_bounds__(1024) void k_scan(
    const int* __restrict__ cnt, int* __restrict__ off,
    int* __restrict__ cur, float* __restrict__ cntf)
{
  __shared__ int ps[1024];
  int t = threadIdx.x;
  int base = t * 16;
  int local[16];
  int s = 0;
  #pragma unroll
  for (int k = 0; k < 16; ++k) { local[k] = s; s += cnt[base + k]; }
  ps[t] = s;
  __syncthreads();
  for (int d = 1; d < 1024; d <<= 1) {
    int v = (t >= d) ? ps[t - d] : 0;
    __syncthreads();
    ps[t] += v;
    __syncthreads();
  }
  int offset = (t == 0) ? 0 : ps[t - 1];
  #pragma unroll
  for (int k = 0; k < 16; ++k) {
    int o = offset + local[k];
    off[base + k] = o;
    cur[base + k] = o;
    cntf[base + k] = (float)cnt[base + k];
  }
  if (t == 1023) off[NA] = offset + s;
}

// ---------------- edge sort: scatter + fused RBF ----------------
__global__ __launch_bounds__(256) void k_scatter(
    const int* __restrict__ ei, const int* __restrict__ ej,
    const float* __restrict__ coords, const float* __restrict__ freq,
    int* __restrict__ cur, int* __restrict__ ej_s, float* __restrict__ rbf_s)
{
  int e = blockIdx.x * 256 + threadIdx.x;
  int i = ei[e], j = ej[e];
  int pos = atomicAdd(&cur[i], 1);
  ej_s[pos] = j;
  float dx = coords[i*3+0] - coords[j*3+0];
  float dy = coords[i*3+1] - coords[j*3+1];
  float dz = coords[i*3+2] - coords[j*3+2];
  float d = sqrtf(dx*dx + dy*dy + dz*dz);
  float u = fmaxf(d * 0.125f, 1e-3f);
  float u2 = u*u, u4 = u2*u2, u5 = u4*u, u6 = u5*u, u7 = u6*u;
  float env = 1.0f/u - 28.0f*u5 + 48.0f*u6 - 21.0f*u7;
  #pragma unroll
  for (int r = 0; r < RB; ++r)
    rbf_s[(size_t)pos*RB + r] = env * sinf(freq[r] * u);
}

// ---------------- per-atom CSR edge pass (no atomics) ----------------
__global__ __launch_bounds__(256) void k_edge_csr(
    const float* __restrict__ P, const float* __restrict__ Q,
    const float* __restrict__ rbf_s, const float* __restrict__ W1c,
    const int* __restrict__ ej_s, const int* __restrict__ off,
    float* __restrict__ Hagg)
{
  __shared__ float w[RB * H];
  for (int idx = threadIdx.x; idx < RB * H; idx += 256) w[idx] = W1c[idx];
  __syncthreads();
  int c = threadIdx.x & 127, half = threadIdx.x >> 7;
  int i = blockIdx.x * 2 + half;
  int e0 = off[i], e1 = off[i + 1];
  float pv = P[(size_t)i * H + c];
  float w0 = w[0*H+c], w1 = w[1*H+c], w2 = w[2*H+c];
  float w3 = w[3*H+c], w4 = w[4*H+c], w5 = w[5*H+c];
  float acc = 0.0f;
  for (int e = e0; e < e1; ++e) {
    int j = ej_s[e];
    float v = pv + Q[(size_t)j * H + c];
    const float* rb = &rbf_s[(size_t)e * RB];
    v += rb[0]*w0 + rb[1]*w1 + rb[2]*w2 + rb[3]*w3 + rb[4]*w4 + rb[5]*w5;
    acc += v / (1.0f + expf(-v));   // silu
  }
  Hagg[(size_t)i * H + c] = acc;
}

// ---------------- generic 128-col GEMM ----------------
// C[m, ccol0+y*ymul+c] = act( (A1|A2)[m,:] @ W[:, wcol0+y*ymul+c] + bias[y*ymul+c]*bias_scale[m] ) + res[m,c]
__global__ __launch_bounds__(256) void gemm128(
    const float* __restrict__ A1, const float* __restrict__ A2,
    const float* __restrict__ W, int ldw, int wcol0,
    const float* __restrict__ bias, const float* __restrict__ bias_scale,
    const float* __restrict__ res,
    float* __restrict__ C, int ldc, int ccol0,
    int M, int Ktot, int act, int ymul)
{
  __shared__ float As[32][256];
  __shared__ float Ws[16][128];
  int tid = threadIdx.x;
  int m0 = blockIdx.x * 32;
  int yoff = blockIdx.y * ymul;
  for (int idx = tid; idx < 32*32; idx += 256) {
    int r = idx >> 5, k4 = idx & 31;
    float4 v = *(const float4*)&A1[(size_t)(m0 + r)*H + k4*4];
    *(float4*)&As[r][k4*4] = v;
  }
  if (A2) {
    for (int idx = tid; idx < 32*32; idx += 256) {
      int r = idx >> 5, k4 = idx & 31;
      float4 v = *(const float4*)&A2[(size_t)(m0 + r)*H + k4*4];
      *(float4*)&As[r][128 + k4*4] = v;
    }
  }
  int rr = tid >> 5;    // 0..7
  int cq = tid & 31;    // col quad
  float acc[4][4] = {};
  for (int kk0 = 0; kk0 < Ktot; kk0 += 16) {
    __syncthreads();
    for (int idx = tid; idx < 16*32; idx += 256) {
      int kr = idx >> 5, c4 = idx & 31;
      float4 v = *(const float4*)&W[(size_t)(kk0 + kr)*ldw + wcol0 + yoff + c4*4];
      *(float4*)&Ws[kr][c4*4] = v;
    }
    __syncthreads();
    #pragma unroll
    for (int kr = 0; kr < 16; ++kr) {
      float4 w = *(const float4*)&Ws[kr][cq*4];
      #pragma unroll
      for (int i = 0; i < 4; ++i) {
        float a = As[rr + 8*i][kk0 + kr];
        acc[i][0] += a * w.x; acc[i][1] += a * w.y;
        acc[i][2] += a * w.z; acc[i][3] += a * w.w;
      }
    }
  }
  #pragma unroll
  for (int i = 0; i < 4; ++i) {
    int m = m0 + rr + 8*i;
    float bs = bias_scale ? bias_scale[m] : 1.0f;
    float4 out;
    float* po = &out.x;
    #pragma unroll
    for (int j = 0; j < 4; ++j) {
      int c = cq*4 + j;
      float v = acc[i][j];
      if (bias) v += bias[yoff + c] * bs;
      if (act == 1) v = v / (1.0f + expf(-v));
      else if (act == 2) v = fmaxf(v, 0.0f);
      if (res) v += res[(size_t)m*H + c];
      po[j] = v;
    }
    *(float4*)&C[(size_t)m*ldc + ccol0 + yoff + cq*4] = out;
  }
}

// ---------------- block mean over K atoms ----------------
__global__ __launch_bounds__(256) void k_block_mean(
    const float* __restrict__ x, float* __restrict__ blocks)
{
  int idx = blockIdx.x * 256 + threadIdx.x;   // over NBLKT*H
  int nb = idx >> 7, h = idx & 127;
  float s = 0.0f;
  #pragma unroll
  for (int k = 0; k < KATOM; ++k)
    s += x[(size_t)(nb*KATOM + k)*H + h];
  blocks[idx] = s * (1.0f / KATOM);
}

// ---------------- block-edge pre-activation gather ----------------
__global__ __launch_bounds__(256) void k_gather_pre(
    const float* __restrict__ Pb, const float* __restrict__ Qb,
    const int* __restrict__ bedges, float* __restrict__ Epre)
{
  int idx = blockIdx.x * 256 + threadIdx.x;   // over BSG*EBE*H
  int row = idx >> 7, c = idx & 127;
  int g = row >> 9;
  int src = bedges[row*2], dst = bedges[row*2 + 1];
  float v = Pb[(size_t)(g*LBLK + src)*H + c] + Qb[(size_t)(g*LBLK + dst)*H + c];
  Epre[idx] = fmaxf(v, 0.0f);
}

__global__ __launch_bounds__(256) void k_cntb(
    const int* __restrict__ bedges, float* __restrict__ cntb)
{
  int idx = blockIdx.x * 256 + threadIdx.x;   // over BSG*EBE
  int g = idx >> 9;
  int src = bedges[idx*2];
  atomAddF(&cntb[g*LBLK + src], 1.0f);
}

// ---------------- MHA v4.1: thread-per-row, key-split, LDS K/V, float4 reads ----
template <int S, int KS>
__global__ __launch_bounds__(256) void k_attn4(
    const float* __restrict__ qkv,
    float* __restrict__ pm, float* __restrict__ pl, float* __restrict__ po)
{
  constexpr int KP = S / KS;       // keys per split
  constexpr int RCH = S / 256;     // row chunks
  __shared__ float Ks[KP][DH];
  __shared__ float Vs[KP][DH];
  int idx = blockIdx.x;
  int rc = idx % RCH;
  int ks = (idx / RCH) % KS;
  int bh = idx / (RCH * KS);
  int b = bh >> 3, h = bh & 7;
  const float* base = qkv + (size_t)b * S * 384;
  int tid = threadIdx.x;
  for (int t = tid; t < KP * 4; t += 256) {
    int j = t >> 2, d4 = t & 3;
    int jg = ks * KP + j;
    *(float4*)&Ks[j][d4*4] = *(const float4*)(base + (size_t)jg*384 + 128 + h*DH + d4*4);
    *(float4*)&Vs[j][d4*4] = *(const float4*)(base + (size_t)jg*384 + 256 + h*DH + d4*4);
  }
  __syncthreads();
  int s = rc * 256 + tid;
  const float4* qp = (const float4*)(base + (size_t)s * 384 + h * DH);
  float4 q0 = qp[0], q1 = qp[1], q2 = qp[2], q3 = qp[3];
  float m = -1e30f;
  #pragma unroll 4
  for (int j = 0; j < KP; ++j) {
    float4 k0 = *(const float4*)&Ks[j][0];
    float4 k1 = *(const float4*)&Ks[j][4];
    float4 k2 = *(const float4*)&Ks[j][8];
    float4 k3 = *(const float4*)&Ks[j][12];
    float s0 = q0.x*k0.x + q0.y*k0.y + q0.z*k0.z + q0.w*k0.w;
    float s1 = q1.x*k1.x + q1.y*k1.y + q1.z*k1.z + q1.w*k1.w;
    float s2 = q2.x*k2.x + q2.y*k2.y + q2.z*k2.z + q2.w*k2.w;
    float s3 = q3.x*k3.x + q3.y*k3.y + q3.z*k3.z + q3.w*k3.w;
    m = fmaxf(m, (s0 + s1) + (s2 + s3));
  }
  float l = 0.0f;
  float4 o0 = {0,0,0,0}, o1 = {0,0,0,0}, o2 = {0,0,0,0}, o3 = {0,0,0,0};
  #pragma unroll 2
  for (int j = 0; j < KP; ++j) {
    float4 k0 = *(const float4*)&Ks[j][0];
    float4 k1 = *(const float4*)&Ks[j][4];
    float4 k2 = *(const float4*)&Ks[j][8];
    float4 k3 = *(const float4*)&Ks[j][12];
    float s0 = q0.x*k0.x + q0.y*k0.y + q0.z*k0.z + q0.w*k0.w;
    float s1 = q1.x*k1.x + q1.y*k1.y + q1.z*k1.z + q1.w*k1.w;
    float s2 = q2.x*k2.x + q2.y*k2.y + q2.z*k2.z + q2.w*k2.w;
    float s3 = q3.x*k3.x + q3.y*k3.y + q3.z*k3.z + q3.w*k3.w;
    float sc = (s0 + s1) + (s2 + s3);
    float p = __expf((sc - m) * 0.25f);   // 1/sqrt(16) folded in
    l += p;
    float4 v0 = *(const float4*)&Vs[j][0];
    float4 v1 = *(const float4*)&Vs[j][4];
    float4 v2 = *(const float4*)&Vs[j][8];
    float4 v3 = *(const float4*)&Vs[j][12];
    o0.x += p*v0.x; o0.y += p*v0.y; o0.z += p*v0.z; o0.w += p*v0.w;
    o1.x += p*v1.x; o1.y += p*v1.y; o1.z += p*v1.z; o1.w += p*v1.w;
    o2.x += p*v2.x; o2.y += p*v2.y; o2.z += p*v2.z; o2.w += p*v2.w;
    o3.x += p*v3.x; o3.y += p*v3.y; o3.z += p*v3.z; o3.w += p*v3.w;
  }
  size_t R = (size_t)bh * S + s;
  size_t pidx = R * KS + ks;
  pm[pidx] = m;
  pl[pidx] = l;
  float* op = po + pidx * DH;
  *(float4*)&op[0]  = o0;
  *(float4*)&op[4]  = o1;
  *(float4*)&op[8]  = o2;
  *(float4*)&op[12] = o3;
}

// combine KS partials per row, then scatter-add
template <int S, int KS>
__global__ __launch_bounds__(256) void k_attn4c(
    const float* __restrict__ pm, const float* __restrict__ pl,
    const float* __restrict__ po,
    const int* __restrict__ bedges, float* __restrict__ outbuf)
{
  int R = blockIdx.x * 256 + threadIdx.x;   // over 128*S rows
  int bh = R / S, s = R % S;
  int b = bh >> 3, h = bh & 7;
  float m = -1e30f;
  float mv[KS];
  #pragma unroll
  for (int k = 0; k < KS; ++k) { mv[k] = pm[(size_t)R*KS + k]; m = fmaxf(m, mv[k]); }
  float l = 0.0f;
  float o[DH] = {};
  #pragma unroll
  for (int k = 0; k < KS; ++k) {
    float sc = __expf((mv[k] - m) * 0.25f);
    l += pl[(size_t)R*KS + k] * sc;
    const float* op = po + ((size_t)R*KS + k) * DH;
    #pragma unroll
    for (int d = 0; d < DH; ++d) o[d] += op[d] * sc;
  }
  float inv = 1.0f / l;
  int src = bedges[((size_t)b * S + s) * 2];
  float* dst = outbuf + (size_t)(b * LBLK + src) * H + h * DH;
  #pragma unroll
  for (int d = 0; d < DH; ++d) atomAddF(&dst[d], o[d] * inv);
}

// ---------------- block self-attention: LDS K/V, 4 heads/block, mean-pool ----
__global__ __launch_bounds__(256) void k_attnS(
    const float* __restrict__ qkv, float* __restrict__ m2)
{
  __shared__ float Ks[4][LBLK][DH];
  __shared__ float Vs[4][LBLK][DH];
  int b = blockIdx.x >> 1, hq = blockIdx.x & 1;
  int tid = threadIdx.x;
  const float* base = qkv + (size_t)b * LBLK * 384;
  for (int t = tid; t < 1024; t += 256) {
    int hl = t >> 8, j = (t >> 2) & 63, d4 = t & 3;
    int h = hq*4 + hl;
    *(float4*)&Ks[hl][j][d4*4] = *(const float4*)(base + (size_t)j*384 + 128 + h*DH + d4*4);
    *(float4*)&Vs[hl][j][d4*4] = *(const float4*)(base + (size_t)j*384 + 256 + h*DH + d4*4);
  }
  __syncthreads();
  int hl = tid >> 6, s = tid & 63;   // hl uniform per wave
  int h = hq*4 + hl;
  const float4* qp = (const float4*)(base + (size_t)s * 384 + h * DH);
  float4 q0 = qp[0], q1 = qp[1], q2 = qp[2], q3 = qp[3];
  float m = -1e30f;
  #pragma unroll 4
  for (int j = 0; j < LBLK; ++j) {
    float4 k0 = *(const float4*)&Ks[hl][j][0];
    float4 k1 = *(const float4*)&Ks[hl][j][4];
    float4 k2 = *(const float4*)&Ks[hl][j][8];
    float4 k3 = *(const float4*)&Ks[hl][j][12];
    float s0 = q0.x*k0.x + q0.y*k0.y + q0.z*k0.z + q0.w*k0.w;
    float s1 = q1.x*k1.x + q1.y*k1.y + q1.z*k1.z + q1.w*k1.w;
    float s2 = q2.x*k2.x + q2.y*k2.y + q2.z*k2.z + q2.w*k2.w;
    float s3 = q3.x*k3.x + q3.y*k3.y + q3.z*k3.z + q3.w*k3.w;
    m = fmaxf(m, (s0 + s1) + (s2 + s3));
  }
  float l = 0.0f;
  float4 o0 = {0,0,0,0}, o1 = {0,0,0,0}, o2 = {0,0,0,0}, o3 = {0,0,0,0};
  #pragma unroll 2
  for (int j = 0; j < LBLK; ++j) {
    float4 k0 = *(const float4*)&Ks[hl][j][0];
    float4 k1 = *(const float4*)&Ks[hl][j][4];
    float4 k2 = *(const float4*)&Ks[hl][j][8];
    float4 k3 = *(const float4*)&Ks[hl][j][12];
    float s0 = q0.x*k0.x + q0.y*k0.y + q0.z*k0.z + q0.w*k0.w;
    float s1 = q1.x*k1.x + q1.y*k1.y + q1.z*k1.z + q1.w*k1.w;
    float s2 = q2.x*k2.x + q2.y*k2.y + q2.z*k2.z + q2.w*k2.w;
    float s3 = q3.x*k3.x + q3.y*k3.y + q3.z*k3.z + q3.w*k3.w;
    float sc = (s0 + s1) + (s2 + s3);
    float p = __expf((sc - m) * 0.25f);
    l += p;
    float4 v0 = *(const float4*)&Vs[hl][j][0];
    float4 v1 = *(const float4*)&Vs[hl][j][4];
    float4 v2 = *(const float4*)&Vs[hl][j][8];
    float4 v3 = *(const float4*)&Vs[hl][j][12];
    o0.x += p*v0.x; o0.y += p*v0.y; o0.z += p*v0.z; o0.w += p*v0.w;
    o1.x += p*v1.x; o1.y += p*v1.y; o1.z += p*v1.z; o1.w += p*v1.w;
    o2.x += p*v2.x; o2.y += p*v2.y; o2.z += p*v2.z; o2.w += p*v2.w;
    o3.x += p*v3.x; o3.y += p*v3.y; o3.z += p*v3.z; o3.w += p*v3.w;
  }
  float inv = (1.0f / l) * (1.0f / 64.0f);
  float* dst = m2 + (size_t)b * H + h * DH;
  float ov[DH] = {o0.x,o0.y,o0.z,o0.w, o1.x,o1.y,o1.z,o1.w,
                  o2.x,o2.y,o2.z,o2.w, o3.x,o3.y,o3.z,o3.w};
  #pragma unroll
  for (int d = 0; d < DH; ++d) atomAddF(&dst[d], ov[d] * inv);
}

__global__ __launch_bounds__(256) void k_scale_bsum(
    float* __restrict__ bsum, const float* __restrict__ cntb,
    float* __restrict__ ind)
{
  int idx = blockIdx.x * 256 + threadIdx.x;   // over NBLKT*H
  int r = idx >> 7;
  float c = cntb[r];
  bsum[idx] = (c > 0.0f) ? bsum[idx] / c : 0.0f;
  if ((idx & 127) == 0) ind[r] = (c > 0.0f) ? 1.0f : 0.0f;
}

// ---------------- final: out-proj + LN + 3-layer MLP ----------------
__device__ __forceinline__ float bsum128(float v, float* red) {
  int t = threadIdx.x;
  red[t] = v; __syncthreads();
  #pragma unroll
  for (int off = 64; off > 0; off >>= 1) {
    if (t < off) red[t] += red[t + off];
    __syncthreads();
  }
  float s = red[0];
  __syncthreads();
  return s;
}

__global__ __launch_bounds__(128) void k_final(
    const float* __restrict__ m2, const float* __restrict__ out_w,
    const float* __restrict__ out_b, const float* __restrict__ lng,
    const float* __restrict__ lnb, const float* __restrict__ w1,
    const float* __restrict__ b1, const float* __restrict__ w2,
    const float* __restrict__ b2, const float* __restrict__ w3,
    const float* __restrict__ b3, float* __restrict__ out)
{
  __shared__ float buf[128];
  __shared__ float red[128];
  int b = blockIdx.x, t = threadIdx.x;
  buf[t] = m2[b*H + t];
  __syncthreads();
  float g = out_b[t];
  for (int k = 0; k < H; ++k) g += buf[k] * out_w[k*H + t];
  float mu = bsum128(g, red) * (1.0f / H);
  float df = g - mu;
  float var = bsum128(df * df, red) * (1.0f / H);
  float gn = df / sqrtf(var + 1e-5f) * lng[t] + lnb[t];
  __syncthreads();
  buf[t] = gn; __syncthreads();
  float h1 = b1[t];
  for (int k = 0; k < H; ++k) h1 += buf[k] * w1[k*H + t];
  h1 = fmaxf(h1, 0.0f);
  __syncthreads();
  buf[t] = h1; __syncthreads();
  float h2 = b2[t];
  for (int k = 0; k < H; ++k) h2 += buf[k] * w2[k*H + t];
  h2 = fmaxf(h2, 0.0f);
  float tot = bsum128(h2 * w3[t], red);
  if (t == 0) out[b] = tot + b3[0];
}

extern "C" void kernel_launch(void* const* d_in, const int* in_sizes, int n_in,
                              void* d_out, int out_size, void* d_ws, size_t ws_size,
                              hipStream_t stream) {
  (void)in_sizes; (void)n_in; (void)out_size; (void)ws_size;
  const int*   A          = (const int*)d_in[0];
  const int*   apos       = (const int*)d_in[1];
  const int*   btypes     = (const int*)d_in[2];
  const float* coords     = (const float*)d_in[3];
  const int*   edge_index = (const int*)d_in[4];
  const int*   bedges     = (const int*)d_in[5];
  const float* emb_atom   = (const float*)d_in[6];
  const float* emb_pos    = (const float*)d_in[7];
  const float* emb_block  = (const float*)d_in[8];
  const float* rbf_freq   = (const float*)d_in[9];
  const float* inter_w1   = (const float*)d_in[10];
  const float* inter_b1   = (const float*)d_in[11];
  const float* inter_w2   = (const float*)d_in[12];
  const float* inter_b2   = (const float*)d_in[13];
  const float* upd_w1     = (const float*)d_in[14];
  const float* upd_b1     = (const float*)d_in[15];
  const float* upd_w2     = (const float*)d_in[16];
  const float* upd_b2     = (const float*)d_in[17];
  const float* edge_w1    = (const float*)d_in[18];
  const float* edge_b1    = (const float*)d_in[19];
  const float* edge_w2    = (const float*)d_in[20];
  const float* edge_b2    = (const float*)d_in[21];
  const float* attn_in_w  = (const float*)d_in[22];
  const float* attn_in_b  = (const float*)d_in[23];
  const float* attn_out_w = (const float*)d_in[24];
  const float* attn_out_b = (const float*)d_in[25];
  const float* ln_g       = (const float*)d_in[26];
  const float* ln_b       = (const float*)d_in[27];
  const float* fin_w1     = (const float*)d_in[28];
  const float* fin_b1     = (const float*)d_in[29];
  const float* fin_w2     = (const float*)d_in[30];
  const float* fin_b2     = (const float*)d_in[31];
  const float* fin_w3     = (const float*)d_in[32];
  const float* fin_b3     = (const float*)d_in[33];
  float* out = (float*)d_out;

  float* ws = (float*)d_ws;
  float* x      = ws + 0;
  float* P      = ws + 2097152;
  float* Q      = ws + 4194304;
  float* Hagg   = ws + 6291456;
  float* rbf_s  = ws + 8388608;    // E*6 (sorted RBF)
  float* cntf   = ws + 9961472;    // NA
  float* blocks = ws + 9977856;    // NBLKT*H
  float* Pb     = ws + 10108928;
  float* Qb     = ws + 10240000;
  float* Epre   = ws + 10371072;   // BSG*EBE*H (also hosts sort scratch early)
  float* ef2    = ws + 11419648;
  float* qkv    = ws + 12468224;   // BSG*EBE*384
  float* bsum   = ws + 15613952;   // NBLKT*H
  float* cntb   = ws + 15745024;   // NBLKT
  float* ind    = ws + 15746048;   // NBLKT
  float* m2     = ws + 15747072;   // BSG*H
  // sort scratch lives in Epre region (dead until block-attention phase):
  int* ej_s = (int*)(ws + 10371072);          // NE ints
  int* off  = (int*)(ws + 10371072 + 262144); // NA+1 ints
  int* cur  = (int*)(ws + 10371072 + 278784); // NA ints
  int* cnt  = (int*)(ws + 10371072 + 295168); // NA ints
  // attention partials reuse dead regions (x, P, Q dead by attention time):
  float* part_m = ws + 0;
  float* part_l = ws + 262144;
  float* part_o = ws + 2097152;

  const int* ei = edge_index;
  const int* ej = edge_index + NE;

  // ---- edge sort (once; reused by both interaction blocks) ----
  (void)hipMemsetAsync(cnt, 0, NA * sizeof(int), stream);
  k_hist<<<NE/256, 256, 0, stream>>>(ei, cnt);
  k_scan<<<1, 1024, 0, stream>>>(cnt, off, cur, cntf);
  k_scatter<<<NE/256, 256, 0, stream>>>(ei, ej, coords, rbf_freq, cur, ej_s, rbf_s);

  k_embed<<<NA*H/256, 256, 0, stream>>>(A, apos, btypes, emb_atom, emb_pos, emb_block, x);

  for (int b = 0; b < NBI; ++b) {
    const float* w1 = inter_w1 + (size_t)b * 262 * H;
    // P = x@W1a + b1 ; Q = x@W1b
    gemm128<<<NA/32, 256, 0, stream>>>(x, nullptr, w1, H, 0, inter_b1 + b*H,
                                       nullptr, nullptr, P, H, 0, NA, H, 0, 0);
    gemm128<<<NA/32, 256, 0, stream>>>(x, nullptr, w1 + 128*H, H, 0, nullptr,
                                       nullptr, nullptr, Q, H, 0, NA, H, 0, 0);
    k_edge_csr<<<NA/2, 256, 0, stream>>>(P, Q, rbf_s, w1 + 256*H, ej_s, off, Hagg);
    // agg = Hagg@W2 + cnt*b2  -> into P
    gemm128<<<NA/32, 256, 0, stream>>>(Hagg, nullptr, inter_w2 + (size_t)b*H*H, H, 0,
                                       inter_b2 + b*H, cntf, nullptr, P, H, 0, NA, H, 0, 0);
    // U = silu([x|agg]@upd_w1 + b1) -> into Q
    gemm128<<<NA/32, 256, 0, stream>>>(x, P, upd_w1 + (size_t)b*2*H*H, H, 0,
                                       upd_b1 + b*H, nullptr, nullptr, Q, H, 0, NA, 2*H, 1, 0);
    // x = U@upd_w2 + b2 + x
    gemm128<<<NA/32, 256, 0, stream>>>(Q, nullptr, upd_w2 + (size_t)b*H*H, H, 0,
                                       upd_b2 + b*H, nullptr, x, x, H, 0, NA, H, 0, 0);
  }

  k_block_mean<<<NBLKT*H/256, 256, 0, stream>>>(x, blocks);
  gemm128<<<NBLKT/32, 256, 0, stream>>>(blocks, nullptr, edge_w1, H, 0, edge_b1,
                                        nullptr, nullptr, Pb, H, 0, NBLKT, H, 0, 0);
  gemm128<<<NBLKT/32, 256, 0, stream>>>(blocks, nullptr, edge_w1 + 128*H, H, 0, nullptr,
                                        nullptr, nullptr, Qb, H, 0, NBLKT, H, 0, 0);
  k_gather_pre<<<BSG*EBE*H/256, 256, 0, stream>>>(Pb, Qb, bedges, Epre);
  gemm128<<<BSG*EBE/32, 256, 0, stream>>>(Epre, nullptr, edge_w2, H, 0, edge_b2,
                                          nullptr, nullptr, ef2, H, 0, BSG*EBE, H, 0, 0);
  gemm128<<<dim3(BSG*EBE/32, 3), 256, 0, stream>>>(ef2, nullptr, attn_in_w, 384, 0,
                                                   attn_in_b, nullptr, nullptr,
                                                   qkv, 384, 0, BSG*EBE, H, 0, 128);
  (void)hipMemsetAsync(bsum, 0, (size_t)(131072 + 1024 + 1024 + 2048) * sizeof(float), stream);
  k_cntb<<<BSG*EBE/256, 256, 0, stream>>>(bedges, cntb);
  k_attn4<EBE, 4><<<BSG*NHD*4*(EBE/256), 256, 0, stream>>>(qkv, part_m, part_l, part_o);
  k_attn4c<EBE, 4><<<BSG*NHD*EBE/256, 256, 0, stream>>>(part_m, part_l, part_o, bedges, bsum);
  k_scale_bsum<<<NBLKT*H/256, 256, 0, stream>>>(bsum, cntb, ind);
  // blocks += (bsum/cnt)@out_w + out_b*[cnt>0]
  gemm128<<<NBLKT/32, 256, 0, stream>>>(bsum, nullptr, attn_out_w, H, 0, attn_out_b,
                                        ind, blocks, blocks, H, 0, NBLKT, H, 0, 0);
  gemm128<<<dim3(NBLKT/32, 3), 256, 0, stream>>>(blocks, nullptr, attn_in_w, 384, 0,
                                                 attn_in_b, nullptr, nullptr,
                                                 qkv, 384, 0, NBLKT, H, 0, 128);
  k_attnS<<<BSG*2, 256, 0, stream>>>(qkv, m2);
  k_final<<<BSG, 128, 0, stream>>>(m2, attn_out_w, attn_out_b, ln_g, ln_b,
                                   fin_w1, fin_b1, fin_w2, fin_b2, fin_w3, fin_b3, out);
}